// Round 1
// baseline (1192.097 us; speedup 1.0000x reference)
//
#include <hip/hip_runtime.h>
#include <math.h>
#include <stdint.h>

// ---------------- utility ----------------
__device__ __forceinline__ float warp_sum64(float v) {
#pragma unroll
  for (int off = 32; off; off >>= 1) v += __shfl_xor(v, off);
  return v;
}

// ---------------- GEMM: C[M,N] = A[M,K] @ B[K,N], fp32 ----------------
// BM=128, BN=64*NCH, BK=16, 256 threads, each thread 8x(4*NCH) outputs.
template<int NCH>
__global__ __launch_bounds__(256) void gemm_kernel(const float* __restrict__ A,
    const float* __restrict__ B, float* __restrict__ C, int M, int N, int K)
{
  constexpr int BN = 64 * NCH;
  __shared__ float As[16][132];       // [k][m], padded: bank = (4k+m)%32
  __shared__ float Bs[16][BN + 4];
  const int tid = threadIdx.x;
  const int tx = tid & 15, ty = tid >> 4;
  const int m0 = blockIdx.x * 128;
  const int n0 = blockIdx.y * BN;
  float acc[2][NCH][4][4] = {};

  for (int k0 = 0; k0 < K; k0 += 16) {
    // A tile 128x16, float4 loads, store transposed
#pragma unroll
    for (int p = 0; p < 2; ++p) {
      int r = (tid >> 2) + p * 64;
      int c = (tid & 3) * 4;
      int gm = m0 + r;
      float4 v = make_float4(0.f, 0.f, 0.f, 0.f);
      if (gm < M) v = *(const float4*)&A[(size_t)gm * K + k0 + c];
      As[c + 0][r] = v.x; As[c + 1][r] = v.y; As[c + 2][r] = v.z; As[c + 3][r] = v.w;
    }
    // B tile 16xBN, float4 loads
#pragma unroll
    for (int p = 0; p < NCH; ++p) {
      constexpr int LPR = BN / 4;            // lanes per row
      int r = tid / LPR + p * (256 / LPR);
      int c = (tid % LPR) * 4;
      float4 v = *(const float4*)&B[(size_t)(k0 + r) * N + n0 + c];
      *(float4*)&Bs[r][c] = v;
    }
    __syncthreads();
#pragma unroll
    for (int k = 0; k < 16; ++k) {
      float av[2][4];
      *(float4*)&av[0][0] = *(const float4*)&As[k][ty * 4];
      *(float4*)&av[1][0] = *(const float4*)&As[k][64 + ty * 4];
#pragma unroll
      for (int ci = 0; ci < NCH; ++ci) {
        float bv[4];
        *(float4*)&bv[0] = *(const float4*)&Bs[k][ci * 64 + tx * 4];
#pragma unroll
        for (int ri = 0; ri < 2; ++ri)
#pragma unroll
          for (int i = 0; i < 4; ++i)
#pragma unroll
            for (int j = 0; j < 4; ++j)
              acc[ri][ci][i][j] = fmaf(av[ri][i], bv[j], acc[ri][ci][i][j]);
      }
    }
    __syncthreads();
  }
#pragma unroll
  for (int ri = 0; ri < 2; ++ri)
#pragma unroll
    for (int i = 0; i < 4; ++i) {
      int gm = m0 + ri * 64 + ty * 4 + i;
      if (gm < M) {
#pragma unroll
        for (int ci = 0; ci < NCH; ++ci) {
          float4 v = make_float4(acc[ri][ci][i][0], acc[ri][ci][i][1],
                                 acc[ri][ci][i][2], acc[ri][ci][i][3]);
          *(float4*)&C[(size_t)gm * N + n0 + ci * 64 + tx * 4] = v;
        }
      }
    }
}

// ---------------- attention logits: al[n][h] = dot(hrow[h*64..], a[h]) ----------------
// block = H*64 threads, one node per block
template<int H>
__global__ void al_kernel(const float* __restrict__ h, const float* __restrict__ a_s,
                          const float* __restrict__ a_d, float* __restrict__ al_s,
                          float* __restrict__ al_d, int N)
{
  int n = blockIdx.x;
  int tid = threadIdx.x;
  int hh = tid >> 6, lane = tid & 63;
  float hv = h[(size_t)n * (H * 64) + tid];
  float ps = hv * a_s[tid];
  float pd = hv * a_d[tid];
  ps = warp_sum64(ps);
  pd = warp_sum64(pd);
  if (lane == 0) { al_s[n * H + hh] = ps; al_d[n * H + hh] = pd; }
}

// ---------------- per-edge exp(leaky_relu) + denominator ----------------
template<int H>
__global__ void edge_kernel(const int* __restrict__ src, const int* __restrict__ dst,
                            int E, int Etot, const float* __restrict__ al_s,
                            const float* __restrict__ al_d, float* __restrict__ ee,
                            float* __restrict__ denom)
{
  int t = blockIdx.x * 256 + threadIdx.x;
  if (t >= Etot * H) return;
  int e = t / H, hh = t - e * H;
  int s, d;
  if (e < E) { s = src[e]; d = dst[e]; } else { s = d = e - E; }
  float x = al_s[s * H + hh] + al_d[d * H + hh];
  x = x > 0.f ? x : 0.2f * x;           // leaky_relu(0.2)
  float v = expf(x);                     // softmax shift-invariant: skip segment max
  ee[t] = v;
  atomicAdd(&denom[d * H + hh], v);
}

// ---------------- CSR build ----------------
__global__ void count_kernel(const int* __restrict__ dst, int E, int Etot, int* __restrict__ counts)
{
  int e = blockIdx.x * 256 + threadIdx.x;
  if (e >= Etot) return;
  int d = (e < E) ? dst[e] : (e - E);
  atomicAdd(&counts[d], 1);
}

__global__ void block_sum_kernel(const int* __restrict__ counts, int N, int* __restrict__ bsums)
{
  __shared__ int sd[256];
  int i = blockIdx.x * 256 + threadIdx.x;
  sd[threadIdx.x] = (i < N) ? counts[i] : 0;
  __syncthreads();
  for (int off = 128; off; off >>= 1) {
    if (threadIdx.x < off) sd[threadIdx.x] += sd[threadIdx.x + off];
    __syncthreads();
  }
  if (threadIdx.x == 0) bsums[blockIdx.x] = sd[0];
}

__global__ void scan_bsums_kernel(int* bsums, int nb)
{
  if (blockIdx.x == 0 && threadIdx.x == 0) {
    int run = 0;
    for (int i = 0; i < nb; ++i) { int v = bsums[i]; bsums[i] = run; run += v; }
  }
}

__global__ void scan_write_kernel(const int* __restrict__ counts, int N,
                                  const int* __restrict__ bsums, int* __restrict__ rowStart, int Etot)
{
  __shared__ int sd[256];
  int i = blockIdx.x * 256 + threadIdx.x;
  int v = (i < N) ? counts[i] : 0;
  sd[threadIdx.x] = v;
  __syncthreads();
  for (int off = 1; off < 256; off <<= 1) {
    int x = (threadIdx.x >= off) ? sd[threadIdx.x - off] : 0;
    __syncthreads();
    sd[threadIdx.x] += x;
    __syncthreads();
  }
  if (i < N) rowStart[i] = bsums[blockIdx.x] + sd[threadIdx.x] - v;  // exclusive
  if (i == N - 1) rowStart[N] = Etot;
}

__global__ void fill_kernel(const int* __restrict__ dst, int E, int Etot,
                            const int* __restrict__ rowStart, int* __restrict__ cursor,
                            int* __restrict__ csrEdge)
{
  int e = blockIdx.x * 256 + threadIdx.x;
  if (e >= Etot) return;
  int d = (e < E) ? dst[e] : (e - E);
  int pos = rowStart[d] + atomicAdd(&cursor[d], 1);
  csrEdge[pos] = e;
}

// ---------------- aggregation: out[n][f] = (sum_e ee*h[src]) / denom (+bias, +elu) ----------------
template<int HC_>
__global__ void aggregate_kernel(const float* __restrict__ h, const float* __restrict__ ee,
                                 const float* __restrict__ denom, const int* __restrict__ src,
                                 int E, const int* __restrict__ rowStart,
                                 const int* __restrict__ csrEdge, float* __restrict__ outp,
                                 int N, const float* __restrict__ bias, int doElu)
{
  constexpr int H_ = HC_ / 64;
  int n = blockIdx.x;
  int f = threadIdx.x;
  int hh = f >> 6;
  float inv = 1.0f / denom[n * H_ + hh];
  float acc = 0.f;
  int end = rowStart[n + 1];
  for (int idx = rowStart[n]; idx < end; ++idx) {
    int e = csrEdge[idx];
    int s = (e < E) ? src[e] : (e - E);
    acc += ee[e * H_ + hh] * h[(size_t)s * HC_ + f];
  }
  acc *= inv;
  if (bias) acc += bias[f];
  if (doElu) acc = acc > 0.f ? acc : expm1f(acc);
  outp[(size_t)n * HC_ + f] = acc;
}

// ---------------- batch norm ----------------
__global__ void bn_stats_kernel(const float* __restrict__ x, int N,
                                float* __restrict__ sums, float* __restrict__ sumsq)
{
  int f = threadIdx.x;  // 256 columns
  int rpb = (N + gridDim.x - 1) / gridDim.x;
  int r0 = blockIdx.x * rpb;
  int r1 = min(N, r0 + rpb);
  float s = 0.f, q = 0.f;
  for (int r = r0; r < r1; ++r) {
    float v = x[(size_t)r * 256 + f];
    s += v; q += v * v;
  }
  atomicAdd(&sums[f], s);
  atomicAdd(&sumsq[f], q);
}

__global__ void bn_final_kernel(const float* __restrict__ sums, const float* __restrict__ sumsq,
                                const float* __restrict__ g, const float* __restrict__ be,
                                int N, float* __restrict__ scale, float* __restrict__ shift)
{
  int f = threadIdx.x;
  float mu = sums[f] / N;
  float var = sumsq[f] / N - mu * mu;
  float rs = rsqrtf(var + 1e-5f);
  float sc = g[f] * rs;
  scale[f] = sc;
  shift[f] = be[f] - mu * sc;
}

__global__ void bn_apply_elu_kernel(float* __restrict__ x, const float* __restrict__ scale,
                                    const float* __restrict__ shift, size_t n4)
{
  size_t i0 = (size_t)blockIdx.x * 256 + threadIdx.x;
  size_t stride = (size_t)gridDim.x * 256;
  for (size_t idx = i0; idx < n4; idx += stride) {
    float4 v = ((const float4*)x)[idx];
    int f = (int)((idx * 4) & 255);
    v.x = v.x * scale[f + 0] + shift[f + 0];
    v.y = v.y * scale[f + 1] + shift[f + 1];
    v.z = v.z * scale[f + 2] + shift[f + 2];
    v.w = v.w * scale[f + 3] + shift[f + 3];
    v.x = v.x > 0.f ? v.x : expm1f(v.x);
    v.y = v.y > 0.f ? v.y : expm1f(v.y);
    v.z = v.z > 0.f ? v.z : expm1f(v.z);
    v.w = v.w > 0.f ? v.w : expm1f(v.w);
    ((float4*)x)[idx] = v;
  }
}

// ---------------- MLP head: out = relu(h@fw1+fb1)@fw2+fb2, wave per node ----------------
__global__ void mlp_kernel(const float* __restrict__ h, const float* __restrict__ fw1,
                           const float* __restrict__ fb1, const float* __restrict__ fw2,
                           const float* __restrict__ fb2, float* __restrict__ out, int N)
{
  int wid = (int)((blockIdx.x * (size_t)blockDim.x + threadIdx.x) >> 6);
  int lane = threadIdx.x & 63;
  if (wid >= N) return;
  float xv = h[(size_t)wid * 64 + lane];
  float hid = 0.f;
#pragma unroll
  for (int j = 0; j < 32; ++j) {
    float p = xv * fw1[lane * 32 + j];
    p = warp_sum64(p);
    if (lane == j) hid = fmaxf(p + fb1[j], 0.f);
  }
  float p0 = hid * fw2[(lane & 31) * 2 + 0];
  float p1 = hid * fw2[(lane & 31) * 2 + 1];
  p0 = warp_sum64(p0);
  p1 = warp_sum64(p1);
  if (lane == 0) {
    out[(size_t)wid * 2 + 0] = p0 + fb2[0];
    out[(size_t)wid * 2 + 1] = p1 + fb2[1];
  }
}

// ---------------- host ----------------
extern "C" void kernel_launch(void* const* d_in, const int* in_sizes, int n_in,
                              void* d_out, int out_size, void* d_ws, size_t ws_size,
                              hipStream_t stream)
{
  const float* x   = (const float*)d_in[0];
  const int*   ei  = (const int*)d_in[1];
  const float* W1  = (const float*)d_in[2];
  const float* a1s = (const float*)d_in[3];
  const float* a1d = (const float*)d_in[4];
  const float* W2  = (const float*)d_in[6];
  const float* a2s = (const float*)d_in[7];
  const float* a2d = (const float*)d_in[8];
  const float* W3  = (const float*)d_in[10];
  const float* a3s = (const float*)d_in[11];
  const float* a3d = (const float*)d_in[12];
  const float* b3  = (const float*)d_in[13];
  const float* g1  = (const float*)d_in[14];
  const float* be1 = (const float*)d_in[15];
  const float* g2  = (const float*)d_in[16];
  const float* be2 = (const float*)d_in[17];
  const float* fw1 = (const float*)d_in[18];
  const float* fb1 = (const float*)d_in[19];
  const float* fw2 = (const float*)d_in[20];
  const float* fb2 = (const float*)d_in[21];
  float* out = (float*)d_out;

  const int F = 128;
  const int N = in_sizes[0] / F;
  const int E = in_sizes[1] / 2;
  const int Etot = E + N;
  const int* srcIdx = ei;
  const int* dstIdx = ei + E;

  // workspace layout (256B aligned slices)
  char* w = (char*)d_ws;
  auto alloc = [&](size_t bytes) -> void* {
    void* p = (void*)w;
    w += (bytes + 255) & ~(size_t)255;
    return p;
  };
  float* h_buf   = (float*)alloc((size_t)N * 256 * 4);
  float* act     = (float*)alloc((size_t)N * 256 * 4);
  float* ee      = (float*)alloc((size_t)Etot * 4 * 4);
  float* als     = (float*)alloc((size_t)N * 4 * 4);
  float* ald     = (float*)alloc((size_t)N * 4 * 4);
  float* denom   = (float*)alloc((size_t)N * 4 * 4);
  int*   counts  = (int*)alloc((size_t)N * 4);
  int*   cursor  = (int*)alloc((size_t)N * 4);
  int*   rowStart= (int*)alloc((size_t)(N + 1) * 4);
  int*   csrE    = (int*)alloc((size_t)Etot * 4);
  int*   bsums   = (int*)alloc((size_t)((N + 255) / 256) * 4);
  float* sums    = (float*)alloc(256 * 4);
  float* sumsq   = (float*)alloc(256 * 4);
  float* scale   = (float*)alloc(256 * 4);
  float* shift   = (float*)alloc(256 * 4);

  const int nb = (N + 255) / 256;
  const int ebk = (Etot + 255) / 256;

  // ---- CSR build (reused by all 3 layers) ----
  hipMemsetAsync(counts, 0, (size_t)N * 4, stream);
  hipMemsetAsync(cursor, 0, (size_t)N * 4, stream);
  count_kernel<<<ebk, 256, 0, stream>>>(dstIdx, E, Etot, counts);
  block_sum_kernel<<<nb, 256, 0, stream>>>(counts, N, bsums);
  scan_bsums_kernel<<<1, 1, 0, stream>>>(bsums, nb);
  scan_write_kernel<<<nb, 256, 0, stream>>>(counts, N, bsums, rowStart, Etot);
  fill_kernel<<<ebk, 256, 0, stream>>>(dstIdx, E, Etot, rowStart, cursor, csrE);

  dim3 gemm_grid2((N + 127) / 128, 2);
  dim3 gemm_grid1((N + 127) / 128, 1);

  // ---- GAT layer 1: x[ N,128 ] -> act[ N,256 ] (bias cancels in BN) ----
  gemm_kernel<2><<<gemm_grid2, 256, 0, stream>>>(x, W1, h_buf, N, 256, F);
  al_kernel<4><<<N, 256, 0, stream>>>(h_buf, a1s, a1d, als, ald, N);
  hipMemsetAsync(denom, 0, (size_t)N * 4 * 4, stream);
  edge_kernel<4><<<(Etot * 4 + 255) / 256, 256, 0, stream>>>(srcIdx, dstIdx, E, Etot, als, ald, ee, denom);
  aggregate_kernel<256><<<N, 256, 0, stream>>>(h_buf, ee, denom, srcIdx, E, rowStart, csrE, act, N, nullptr, 0);
  // BN1 + ELU (in place on act)
  hipMemsetAsync(sums, 0, 256 * 4, stream);
  hipMemsetAsync(sumsq, 0, 256 * 4, stream);
  bn_stats_kernel<<<128, 256, 0, stream>>>(act, N, sums, sumsq);
  bn_final_kernel<<<1, 256, 0, stream>>>(sums, sumsq, g1, be1, N, scale, shift);
  bn_apply_elu_kernel<<<1024, 256, 0, stream>>>(act, scale, shift, (size_t)N * 64);

  // ---- GAT layer 2: act[ N,256 ] -> act[ N,256 ] ----
  gemm_kernel<2><<<gemm_grid2, 256, 0, stream>>>(act, W2, h_buf, N, 256, 256);
  al_kernel<4><<<N, 256, 0, stream>>>(h_buf, a2s, a2d, als, ald, N);
  hipMemsetAsync(denom, 0, (size_t)N * 4 * 4, stream);
  edge_kernel<4><<<(Etot * 4 + 255) / 256, 256, 0, stream>>>(srcIdx, dstIdx, E, Etot, als, ald, ee, denom);
  aggregate_kernel<256><<<N, 256, 0, stream>>>(h_buf, ee, denom, srcIdx, E, rowStart, csrE, act, N, nullptr, 0);
  // BN2 + ELU
  hipMemsetAsync(sums, 0, 256 * 4, stream);
  hipMemsetAsync(sumsq, 0, 256 * 4, stream);
  bn_stats_kernel<<<128, 256, 0, stream>>>(act, N, sums, sumsq);
  bn_final_kernel<<<1, 256, 0, stream>>>(sums, sumsq, g2, be2, N, scale, shift);
  bn_apply_elu_kernel<<<1024, 256, 0, stream>>>(act, scale, shift, (size_t)N * 64);

  // ---- GAT layer 3 (1 head, C=64): act[ N,256 ] -> act[ N,64 ] with +b3, ELU ----
  gemm_kernel<1><<<gemm_grid1, 256, 0, stream>>>(act, W3, h_buf, N, 64, 256);
  al_kernel<1><<<N, 64, 0, stream>>>(h_buf, a3s, a3d, als, ald, N);
  hipMemsetAsync(denom, 0, (size_t)N * 4, stream);
  edge_kernel<1><<<(Etot + 255) / 256, 256, 0, stream>>>(srcIdx, dstIdx, E, Etot, als, ald, ee, denom);
  aggregate_kernel<64><<<N, 64, 0, stream>>>(h_buf, ee, denom, srcIdx, E, rowStart, csrE, act, N, b3, 1);

  // ---- MLP head ----
  mlp_kernel<<<(N + 3) / 4, 256, 0, stream>>>(act, fw1, fb1, fw2, fb2, out, N);
}

// Round 2
// 1073.050 us; speedup vs baseline: 1.1109x; 1.1109x over previous
//
#include <hip/hip_runtime.h>
#include <math.h>
#include <stdint.h>

// ---------------- utility ----------------
__device__ __forceinline__ float warp_sum64(float v) {
#pragma unroll
  for (int off = 32; off; off >>= 1) v += __shfl_xor(v, off);
  return v;
}

// ---------------- GEMM: C[M,N] = A[M,K] @ B[K,N], fp32 ----------------
// BM=128, BN=64*NCH, BK=16, 256 threads, each thread 8x(4*NCH) outputs.
template<int NCH>
__global__ __launch_bounds__(256) void gemm_kernel(const float* __restrict__ A,
    const float* __restrict__ B, float* __restrict__ C, int M, int N, int K)
{
  constexpr int BN = 64 * NCH;
  __shared__ float As[16][132];       // [k][m], padded: bank = (4k+m)%32
  __shared__ float Bs[16][BN + 4];
  const int tid = threadIdx.x;
  const int tx = tid & 15, ty = tid >> 4;
  const int m0 = blockIdx.x * 128;
  const int n0 = blockIdx.y * BN;
  float acc[2][NCH][4][4] = {};

  for (int k0 = 0; k0 < K; k0 += 16) {
    // A tile 128x16, float4 loads, store transposed
#pragma unroll
    for (int p = 0; p < 2; ++p) {
      int r = (tid >> 2) + p * 64;
      int c = (tid & 3) * 4;
      int gm = m0 + r;
      float4 v = make_float4(0.f, 0.f, 0.f, 0.f);
      if (gm < M) v = *(const float4*)&A[(size_t)gm * K + k0 + c];
      As[c + 0][r] = v.x; As[c + 1][r] = v.y; As[c + 2][r] = v.z; As[c + 3][r] = v.w;
    }
    // B tile 16xBN, float4 loads
#pragma unroll
    for (int p = 0; p < NCH; ++p) {
      constexpr int LPR = BN / 4;            // lanes per row
      int r = tid / LPR + p * (256 / LPR);
      int c = (tid % LPR) * 4;
      float4 v = *(const float4*)&B[(size_t)(k0 + r) * N + n0 + c];
      *(float4*)&Bs[r][c] = v;
    }
    __syncthreads();
#pragma unroll
    for (int k = 0; k < 16; ++k) {
      float av[2][4];
      *(float4*)&av[0][0] = *(const float4*)&As[k][ty * 4];
      *(float4*)&av[1][0] = *(const float4*)&As[k][64 + ty * 4];
#pragma unroll
      for (int ci = 0; ci < NCH; ++ci) {
        float bv[4];
        *(float4*)&bv[0] = *(const float4*)&Bs[k][ci * 64 + tx * 4];
#pragma unroll
        for (int ri = 0; ri < 2; ++ri)
#pragma unroll
          for (int i = 0; i < 4; ++i)
#pragma unroll
            for (int j = 0; j < 4; ++j)
              acc[ri][ci][i][j] = fmaf(av[ri][i], bv[j], acc[ri][ci][i][j]);
      }
    }
    __syncthreads();
  }
#pragma unroll
  for (int ri = 0; ri < 2; ++ri)
#pragma unroll
    for (int i = 0; i < 4; ++i) {
      int gm = m0 + ri * 64 + ty * 4 + i;
      if (gm < M) {
#pragma unroll
        for (int ci = 0; ci < NCH; ++ci) {
          float4 v = make_float4(acc[ri][ci][i][0], acc[ri][ci][i][1],
                                 acc[ri][ci][i][2], acc[ri][ci][i][3]);
          *(float4*)&C[(size_t)gm * N + n0 + ci * 64 + tx * 4] = v;
        }
      }
    }
}

// ---------------- attention logits: al[n][h] = dot(hrow[h*64..], a[h]) ----------------
// block = H*64 threads, one node per block
template<int H>
__global__ void al_kernel(const float* __restrict__ h, const float* __restrict__ a_s,
                          const float* __restrict__ a_d, float* __restrict__ al_s,
                          float* __restrict__ al_d, int N)
{
  int n = blockIdx.x;
  int tid = threadIdx.x;
  int hh = tid >> 6, lane = tid & 63;
  float hv = h[(size_t)n * (H * 64) + tid];
  float ps = hv * a_s[tid];
  float pd = hv * a_d[tid];
  ps = warp_sum64(ps);
  pd = warp_sum64(pd);
  if (lane == 0) { al_s[n * H + hh] = ps; al_d[n * H + hh] = pd; }
}

// ---------------- per-edge exp(leaky_relu) + denominator ----------------
template<int H>
__global__ void edge_kernel(const int* __restrict__ src, const int* __restrict__ dst,
                            int E, int Etot, const float* __restrict__ al_s,
                            const float* __restrict__ al_d, float* __restrict__ ee,
                            float* __restrict__ denom)
{
  int t = blockIdx.x * 256 + threadIdx.x;
  if (t >= Etot * H) return;
  int e = t / H, hh = t - e * H;
  int s, d;
  if (e < E) { s = src[e]; d = dst[e]; } else { s = d = e - E; }
  float x = al_s[s * H + hh] + al_d[d * H + hh];
  x = x > 0.f ? x : 0.2f * x;           // leaky_relu(0.2)
  float v = expf(x);                     // softmax shift-invariant: skip segment max
  ee[t] = v;
  atomicAdd(&denom[d * H + hh], v);
}

// ---------------- CSR build ----------------
__global__ void count_kernel(const int* __restrict__ dst, int E, int Etot, int* __restrict__ counts)
{
  int e = blockIdx.x * 256 + threadIdx.x;
  if (e >= Etot) return;
  int d = (e < E) ? dst[e] : (e - E);
  atomicAdd(&counts[d], 1);
}

__global__ void block_sum_kernel(const int* __restrict__ counts, int N, int* __restrict__ bsums)
{
  __shared__ int sd[256];
  int i = blockIdx.x * 256 + threadIdx.x;
  sd[threadIdx.x] = (i < N) ? counts[i] : 0;
  __syncthreads();
  for (int off = 128; off; off >>= 1) {
    if (threadIdx.x < off) sd[threadIdx.x] += sd[threadIdx.x + off];
    __syncthreads();
  }
  if (threadIdx.x == 0) bsums[blockIdx.x] = sd[0];
}

__global__ void scan_bsums_kernel(int* bsums, int nb)
{
  if (blockIdx.x == 0 && threadIdx.x == 0) {
    int run = 0;
    for (int i = 0; i < nb; ++i) { int v = bsums[i]; bsums[i] = run; run += v; }
  }
}

__global__ void scan_write_kernel(const int* __restrict__ counts, int N,
                                  const int* __restrict__ bsums, int* __restrict__ rowStart, int Etot)
{
  __shared__ int sd[256];
  int i = blockIdx.x * 256 + threadIdx.x;
  int v = (i < N) ? counts[i] : 0;
  sd[threadIdx.x] = v;
  __syncthreads();
  for (int off = 1; off < 256; off <<= 1) {
    int x = (threadIdx.x >= off) ? sd[threadIdx.x - off] : 0;
    __syncthreads();
    sd[threadIdx.x] += x;
    __syncthreads();
  }
  if (i < N) rowStart[i] = bsums[blockIdx.x] + sd[threadIdx.x] - v;  // exclusive
  if (i == N - 1) rowStart[N] = Etot;
}

__global__ void fill_kernel(const int* __restrict__ dst, int E, int Etot,
                            const int* __restrict__ rowStart, int* __restrict__ cursor,
                            int* __restrict__ csrEdge)
{
  int e = blockIdx.x * 256 + threadIdx.x;
  if (e >= Etot) return;
  int d = (e < E) ? dst[e] : (e - E);
  int pos = rowStart[d] + atomicAdd(&cursor[d], 1);
  csrEdge[pos] = e;
}

// ---------------- aggregation: out[n][f] = (sum_e ee*h[src]) / denom (+bias, +elu) ----------------
template<int HC_>
__global__ void aggregate_kernel(const float* __restrict__ h, const float* __restrict__ ee,
                                 const float* __restrict__ denom, const int* __restrict__ src,
                                 int E, const int* __restrict__ rowStart,
                                 const int* __restrict__ csrEdge, float* __restrict__ outp,
                                 int N, const float* __restrict__ bias, int doElu)
{
  constexpr int H_ = HC_ / 64;
  int n = blockIdx.x;
  int f = threadIdx.x;
  int hh = f >> 6;
  float inv = 1.0f / denom[n * H_ + hh];
  float acc = 0.f;
  int end = rowStart[n + 1];
  for (int idx = rowStart[n]; idx < end; ++idx) {
    int e = csrEdge[idx];
    int s = (e < E) ? src[e] : (e - E);
    acc += ee[e * H_ + hh] * h[(size_t)s * HC_ + f];
  }
  acc *= inv;
  if (bias) acc += bias[f];
  if (doElu) acc = acc > 0.f ? acc : expm1f(acc);
  outp[(size_t)n * HC_ + f] = acc;
}

// ---------------- batch norm ----------------
__global__ void bn_stats_kernel(const float* __restrict__ x, int N,
                                float* __restrict__ sums, float* __restrict__ sumsq)
{
  int f = threadIdx.x;  // 256 columns
  int rpb = (N + gridDim.x - 1) / gridDim.x;
  int r0 = blockIdx.x * rpb;
  int r1 = min(N, r0 + rpb);
  float s = 0.f, q = 0.f;
  for (int r = r0; r < r1; ++r) {
    float v = x[(size_t)r * 256 + f];
    s += v; q += v * v;
  }
  atomicAdd(&sums[f], s);
  atomicAdd(&sumsq[f], q);
}

__global__ void bn_final_kernel(const float* __restrict__ sums, const float* __restrict__ sumsq,
                                const float* __restrict__ g, const float* __restrict__ be,
                                int N, float* __restrict__ scale, float* __restrict__ shift)
{
  int f = threadIdx.x;
  float mu = sums[f] / N;
  float var = sumsq[f] / N - mu * mu;
  float rs = rsqrtf(var + 1e-5f);
  float sc = g[f] * rs;
  scale[f] = sc;
  shift[f] = be[f] - mu * sc;
}

__global__ void bn_apply_elu_kernel(float* __restrict__ x, const float* __restrict__ scale,
                                    const float* __restrict__ shift, size_t n4)
{
  size_t i0 = (size_t)blockIdx.x * 256 + threadIdx.x;
  size_t stride = (size_t)gridDim.x * 256;
  for (size_t idx = i0; idx < n4; idx += stride) {
    float4 v = ((const float4*)x)[idx];
    int f = (int)((idx * 4) & 255);
    v.x = v.x * scale[f + 0] + shift[f + 0];
    v.y = v.y * scale[f + 1] + shift[f + 1];
    v.z = v.z * scale[f + 2] + shift[f + 2];
    v.w = v.w * scale[f + 3] + shift[f + 3];
    v.x = v.x > 0.f ? v.x : expm1f(v.x);
    v.y = v.y > 0.f ? v.y : expm1f(v.y);
    v.z = v.z > 0.f ? v.z : expm1f(v.z);
    v.w = v.w > 0.f ? v.w : expm1f(v.w);
    ((float4*)x)[idx] = v;
  }
}

// ---------------- MLP head: out = relu(h@fw1+fb1)@fw2+fb2 ----------------
// Wave per node (grid-stride). Lane l owns hidden unit j=l&31 and output col=l>>5.
// fw1 column j preloaded into 64 regs; per node: 64x {broadcast shfl + fma}.
__global__ __launch_bounds__(256) void mlp_kernel(const float* __restrict__ h,
                           const float* __restrict__ fw1,
                           const float* __restrict__ fb1, const float* __restrict__ fw2,
                           const float* __restrict__ fb2, float* __restrict__ out, int N)
{
  const int lane = threadIdx.x & 63;
  const int j = lane & 31;        // hidden unit owned by this lane
  const int col = lane >> 5;      // output column (0 or 1)
  float w1c[64];
#pragma unroll
  for (int k = 0; k < 64; ++k) w1c[k] = fw1[k * 32 + j];   // coalesced per k
  const float b1v = fb1[j];
  const float w2v = fw2[j * 2 + col];
  const float b2v = fb2[col];

  const int nwaves = (int)(gridDim.x * (blockDim.x >> 6));
  int wid = (int)(blockIdx.x * (blockDim.x >> 6) + (threadIdx.x >> 6));
  for (int n = wid; n < N; n += nwaves) {
    float hv = h[(size_t)n * 64 + lane];   // lane k holds h[n][k]
    float acc = 0.f;
#pragma unroll
    for (int k = 0; k < 64; ++k) {
      float s = __shfl(hv, k);             // broadcast -> v_readlane, independent
      acc = fmaf(s, w1c[k], acc);
    }
    float hid = fmaxf(acc + b1v, 0.f);
    float p = hid * w2v;
#pragma unroll
    for (int off = 16; off; off >>= 1) p += __shfl_xor(p, off);  // reduce within 32-half
    if (j == 0) out[(size_t)n * 2 + col] = p + b2v;
  }
}

// ---------------- host ----------------
extern "C" void kernel_launch(void* const* d_in, const int* in_sizes, int n_in,
                              void* d_out, int out_size, void* d_ws, size_t ws_size,
                              hipStream_t stream)
{
  const float* x   = (const float*)d_in[0];
  const int*   ei  = (const int*)d_in[1];
  const float* W1  = (const float*)d_in[2];
  const float* a1s = (const float*)d_in[3];
  const float* a1d = (const float*)d_in[4];
  const float* W2  = (const float*)d_in[6];
  const float* a2s = (const float*)d_in[7];
  const float* a2d = (const float*)d_in[8];
  const float* W3  = (const float*)d_in[10];
  const float* a3s = (const float*)d_in[11];
  const float* a3d = (const float*)d_in[12];
  const float* b3  = (const float*)d_in[13];
  const float* g1  = (const float*)d_in[14];
  const float* be1 = (const float*)d_in[15];
  const float* g2  = (const float*)d_in[16];
  const float* be2 = (const float*)d_in[17];
  const float* fw1 = (const float*)d_in[18];
  const float* fb1 = (const float*)d_in[19];
  const float* fw2 = (const float*)d_in[20];
  const float* fb2 = (const float*)d_in[21];
  float* out = (float*)d_out;

  const int F = 128;
  const int N = in_sizes[0] / F;
  const int E = in_sizes[1] / 2;
  const int Etot = E + N;
  const int* srcIdx = ei;
  const int* dstIdx = ei + E;

  // workspace layout (256B aligned slices)
  char* w = (char*)d_ws;
  auto alloc = [&](size_t bytes) -> void* {
    void* p = (void*)w;
    w += (bytes + 255) & ~(size_t)255;
    return p;
  };
  float* h_buf   = (float*)alloc((size_t)N * 256 * 4);
  float* act     = (float*)alloc((size_t)N * 256 * 4);
  float* ee      = (float*)alloc((size_t)Etot * 4 * 4);
  float* als     = (float*)alloc((size_t)N * 4 * 4);
  float* ald     = (float*)alloc((size_t)N * 4 * 4);
  float* denom   = (float*)alloc((size_t)N * 4 * 4);
  int*   counts  = (int*)alloc((size_t)N * 4);
  int*   cursor  = (int*)alloc((size_t)N * 4);
  int*   rowStart= (int*)alloc((size_t)(N + 1) * 4);
  int*   csrE    = (int*)alloc((size_t)Etot * 4);
  int*   bsums   = (int*)alloc((size_t)((N + 255) / 256) * 4);
  float* sums    = (float*)alloc(256 * 4);
  float* sumsq   = (float*)alloc(256 * 4);
  float* scale   = (float*)alloc(256 * 4);
  float* shift   = (float*)alloc(256 * 4);

  const int nb = (N + 255) / 256;
  const int ebk = (Etot + 255) / 256;

  // ---- CSR build (reused by all 3 layers) ----
  hipMemsetAsync(counts, 0, (size_t)N * 4, stream);
  hipMemsetAsync(cursor, 0, (size_t)N * 4, stream);
  count_kernel<<<ebk, 256, 0, stream>>>(dstIdx, E, Etot, counts);
  block_sum_kernel<<<nb, 256, 0, stream>>>(counts, N, bsums);
  scan_bsums_kernel<<<1, 1, 0, stream>>>(bsums, nb);
  scan_write_kernel<<<nb, 256, 0, stream>>>(counts, N, bsums, rowStart, Etot);
  fill_kernel<<<ebk, 256, 0, stream>>>(dstIdx, E, Etot, rowStart, cursor, csrE);

  dim3 gemm_grid2((N + 127) / 128, 2);
  dim3 gemm_grid1((N + 127) / 128, 1);

  // ---- GAT layer 1: x[ N,128 ] -> act[ N,256 ] (bias cancels in BN) ----
  gemm_kernel<2><<<gemm_grid2, 256, 0, stream>>>(x, W1, h_buf, N, 256, F);
  al_kernel<4><<<N, 256, 0, stream>>>(h_buf, a1s, a1d, als, ald, N);
  hipMemsetAsync(denom, 0, (size_t)N * 4 * 4, stream);
  edge_kernel<4><<<(Etot * 4 + 255) / 256, 256, 0, stream>>>(srcIdx, dstIdx, E, Etot, als, ald, ee, denom);
  aggregate_kernel<256><<<N, 256, 0, stream>>>(h_buf, ee, denom, srcIdx, E, rowStart, csrE, act, N, nullptr, 0);
  // BN1 + ELU (in place on act)
  hipMemsetAsync(sums, 0, 256 * 4, stream);
  hipMemsetAsync(sumsq, 0, 256 * 4, stream);
  bn_stats_kernel<<<128, 256, 0, stream>>>(act, N, sums, sumsq);
  bn_final_kernel<<<1, 256, 0, stream>>>(sums, sumsq, g1, be1, N, scale, shift);
  bn_apply_elu_kernel<<<1024, 256, 0, stream>>>(act, scale, shift, (size_t)N * 64);

  // ---- GAT layer 2: act[ N,256 ] -> act[ N,256 ] ----
  gemm_kernel<2><<<gemm_grid2, 256, 0, stream>>>(act, W2, h_buf, N, 256, 256);
  al_kernel<4><<<N, 256, 0, stream>>>(h_buf, a2s, a2d, als, ald, N);
  hipMemsetAsync(denom, 0, (size_t)N * 4 * 4, stream);
  edge_kernel<4><<<(Etot * 4 + 255) / 256, 256, 0, stream>>>(srcIdx, dstIdx, E, Etot, als, ald, ee, denom);
  aggregate_kernel<256><<<N, 256, 0, stream>>>(h_buf, ee, denom, srcIdx, E, rowStart, csrE, act, N, nullptr, 0);
  // BN2 + ELU
  hipMemsetAsync(sums, 0, 256 * 4, stream);
  hipMemsetAsync(sumsq, 0, 256 * 4, stream);
  bn_stats_kernel<<<128, 256, 0, stream>>>(act, N, sums, sumsq);
  bn_final_kernel<<<1, 256, 0, stream>>>(sums, sumsq, g2, be2, N, scale, shift);
  bn_apply_elu_kernel<<<1024, 256, 0, stream>>>(act, scale, shift, (size_t)N * 64);

  // ---- GAT layer 3 (1 head, C=64): act[ N,256 ] -> act[ N,64 ] with +b3, ELU ----
  gemm_kernel<1><<<gemm_grid1, 256, 0, stream>>>(act, W3, h_buf, N, 64, 256);
  al_kernel<1><<<N, 64, 0, stream>>>(h_buf, a3s, a3d, als, ald, N);
  hipMemsetAsync(denom, 0, (size_t)N * 4, stream);
  edge_kernel<1><<<(Etot + 255) / 256, 256, 0, stream>>>(srcIdx, dstIdx, E, Etot, als, ald, ee, denom);
  aggregate_kernel<64><<<N, 64, 0, stream>>>(h_buf, ee, denom, srcIdx, E, rowStart, csrE, act, N, b3, 1);

  // ---- MLP head ----
  mlp_kernel<<<1024, 256, 0, stream>>>(act, fw1, fb1, fw2, fb2, out, N);
}

// Round 3
// 744.479 us; speedup vs baseline: 1.6013x; 1.4413x over previous
//
#include <hip/hip_runtime.h>
#include <math.h>
#include <stdint.h>

// ---------------- utility ----------------
__device__ __forceinline__ float warp_sum64(float v) {
#pragma unroll
  for (int off = 32; off; off >>= 1) v += __shfl_xor(v, off);
  return v;
}

__device__ __forceinline__ float bf2f(unsigned short u) {
  return __uint_as_float((unsigned int)u << 16);
}
__device__ __forceinline__ unsigned short f2bf(float f) {   // RNE
  unsigned int u = __float_as_uint(f);
  unsigned int r = (u + 0x7FFFu + ((u >> 16) & 1u)) >> 16;
  return (unsigned short)r;
}

// ---------------- GEMM: C[M,N] = A[M,K] @ B[K,N], fp32 in, bf16 out ----------------
// BM=128, BN=64*NCH, BK=16, 256 threads, each thread 8x(4*NCH) outputs.
template<int NCH>
__global__ __launch_bounds__(256) void gemm_kernel(const float* __restrict__ A,
    const float* __restrict__ B, unsigned short* __restrict__ C, int M, int N, int K)
{
  constexpr int BN = 64 * NCH;
  __shared__ float As[16][132];       // [k][m], padded
  __shared__ float Bs[16][BN + 4];
  const int tid = threadIdx.x;
  const int tx = tid & 15, ty = tid >> 4;
  const int m0 = blockIdx.x * 128;
  const int n0 = blockIdx.y * BN;
  float acc[2][NCH][4][4] = {};

  for (int k0 = 0; k0 < K; k0 += 16) {
#pragma unroll
    for (int p = 0; p < 2; ++p) {
      int r = (tid >> 2) + p * 64;
      int c = (tid & 3) * 4;
      int gm = m0 + r;
      float4 v = make_float4(0.f, 0.f, 0.f, 0.f);
      if (gm < M) v = *(const float4*)&A[(size_t)gm * K + k0 + c];
      As[c + 0][r] = v.x; As[c + 1][r] = v.y; As[c + 2][r] = v.z; As[c + 3][r] = v.w;
    }
#pragma unroll
    for (int p = 0; p < NCH; ++p) {
      constexpr int LPR = BN / 4;
      int r = tid / LPR + p * (256 / LPR);
      int c = (tid % LPR) * 4;
      float4 v = *(const float4*)&B[(size_t)(k0 + r) * N + n0 + c];
      *(float4*)&Bs[r][c] = v;
    }
    __syncthreads();
#pragma unroll
    for (int k = 0; k < 16; ++k) {
      float av[2][4];
      *(float4*)&av[0][0] = *(const float4*)&As[k][ty * 4];
      *(float4*)&av[1][0] = *(const float4*)&As[k][64 + ty * 4];
#pragma unroll
      for (int ci = 0; ci < NCH; ++ci) {
        float bv[4];
        *(float4*)&bv[0] = *(const float4*)&Bs[k][ci * 64 + tx * 4];
#pragma unroll
        for (int ri = 0; ri < 2; ++ri)
#pragma unroll
          for (int i = 0; i < 4; ++i)
#pragma unroll
            for (int j = 0; j < 4; ++j)
              acc[ri][ci][i][j] = fmaf(av[ri][i], bv[j], acc[ri][ci][i][j]);
      }
    }
    __syncthreads();
  }
#pragma unroll
  for (int ri = 0; ri < 2; ++ri)
#pragma unroll
    for (int i = 0; i < 4; ++i) {
      int gm = m0 + ri * 64 + ty * 4 + i;
      if (gm < M) {
#pragma unroll
        for (int ci = 0; ci < NCH; ++ci) {
          ushort4 o;
          o.x = f2bf(acc[ri][ci][i][0]);
          o.y = f2bf(acc[ri][ci][i][1]);
          o.z = f2bf(acc[ri][ci][i][2]);
          o.w = f2bf(acc[ri][ci][i][3]);
          *(ushort4*)&C[(size_t)gm * N + n0 + ci * 64 + tx * 4] = o;
        }
      }
    }
}

// ---------------- attention logits from bf16 h ----------------
template<int H>
__global__ void al_kernel(const unsigned short* __restrict__ h, const float* __restrict__ a_s,
                          const float* __restrict__ a_d, float* __restrict__ al_s,
                          float* __restrict__ al_d, int N)
{
  int n = blockIdx.x;
  int tid = threadIdx.x;
  int hh = tid >> 6, lane = tid & 63;
  float hv = bf2f(h[(size_t)n * (H * 64) + tid]);
  float ps = hv * a_s[tid];
  float pd = hv * a_d[tid];
  ps = warp_sum64(ps);
  pd = warp_sum64(pd);
  if (lane == 0) { al_s[n * H + hh] = ps; al_d[n * H + hh] = pd; }
}

// ---------------- per-position exp(leaky_relu), CSR order, no atomics ----------------
template<int H>
__global__ void edge_kernel(const int* __restrict__ csrSrc, const int* __restrict__ csrDst,
                            int Etot, const float* __restrict__ al_s,
                            const float* __restrict__ al_d, float* __restrict__ eeCsr)
{
  int t = blockIdx.x * 256 + threadIdx.x;
  if (t >= Etot * H) return;
  int pos = t / H, hh = t - pos * H;
  int s = csrSrc[pos], d = csrDst[pos];
  float x = al_s[s * H + hh] + al_d[d * H + hh];
  x = x > 0.f ? x : 0.2f * x;           // leaky_relu(0.2)
  eeCsr[t] = expf(x);                    // softmax shift-invariant: skip segment max
}

// ---------------- CSR build ----------------
__global__ void count_kernel(const int* __restrict__ dst, int E, int Etot, int* __restrict__ counts)
{
  int e = blockIdx.x * 256 + threadIdx.x;
  if (e >= Etot) return;
  int d = (e < E) ? dst[e] : (e - E);
  atomicAdd(&counts[d], 1);
}

__global__ void block_sum_kernel(const int* __restrict__ counts, int N, int* __restrict__ bsums)
{
  __shared__ int sd[256];
  int i = blockIdx.x * 256 + threadIdx.x;
  sd[threadIdx.x] = (i < N) ? counts[i] : 0;
  __syncthreads();
  for (int off = 128; off; off >>= 1) {
    if (threadIdx.x < off) sd[threadIdx.x] += sd[threadIdx.x + off];
    __syncthreads();
  }
  if (threadIdx.x == 0) bsums[blockIdx.x] = sd[0];
}

__global__ void scan_bsums_kernel(int* bsums, int nb)
{
  if (blockIdx.x == 0 && threadIdx.x == 0) {
    int run = 0;
    for (int i = 0; i < nb; ++i) { int v = bsums[i]; bsums[i] = run; run += v; }
  }
}

__global__ void scan_write_kernel(const int* __restrict__ counts, int N,
                                  const int* __restrict__ bsums, int* __restrict__ rowStart, int Etot)
{
  __shared__ int sd[256];
  int i = blockIdx.x * 256 + threadIdx.x;
  int v = (i < N) ? counts[i] : 0;
  sd[threadIdx.x] = v;
  __syncthreads();
  for (int off = 1; off < 256; off <<= 1) {
    int x = (threadIdx.x >= off) ? sd[threadIdx.x - off] : 0;
    __syncthreads();
    sd[threadIdx.x] += x;
    __syncthreads();
  }
  if (i < N) rowStart[i] = bsums[blockIdx.x] + sd[threadIdx.x] - v;  // exclusive
  if (i == N - 1) rowStart[N] = Etot;
}

__global__ void fill_kernel(const int* __restrict__ src, const int* __restrict__ dst,
                            int E, int Etot, const int* __restrict__ rowStart,
                            int* __restrict__ cursor, int* __restrict__ csrSrc,
                            int* __restrict__ csrDst)
{
  int e = blockIdx.x * 256 + threadIdx.x;
  if (e >= Etot) return;
  int s, d;
  if (e < E) { s = src[e]; d = dst[e]; } else { s = d = e - E; }
  int pos = rowStart[d] + atomicAdd(&cursor[d], 1);
  csrSrc[pos] = s;
  csrDst[pos] = d;
}

// ---------------- aggregation: wave per node, bf16 gather, inline denom ----------------
// out[n][f] = (sum_pos w*h[src]) / (sum_pos w)  (+bias, +elu)
template<int HC_>
__global__ __launch_bounds__(256) void aggregate_kernel(
    const unsigned short* __restrict__ h16, const float* __restrict__ eeCsr,
    const int* __restrict__ csrSrc, const int* __restrict__ rowStart,
    float* __restrict__ outp, int N, const float* __restrict__ bias, int doElu)
{
  constexpr int H_ = HC_ / 64;       // heads (4 or 1)
  constexpr int FPL = HC_ / 64;      // features per lane (4 or 1)
  int wid = (int)(blockIdx.x * (blockDim.x >> 6) + (threadIdx.x >> 6));
  if (wid >= N) return;
  const int lane = threadIdx.x & 63;
  const int head = (H_ == 4) ? (lane >> 4) : 0;
  const int start = rowStart[wid], end = rowStart[wid + 1];

  float acc[FPL] = {};
  float wsum = 0.f;

  for (int base = start; base < end; base += 64) {
    int cnt = end - base; if (cnt > 64) cnt = 64;
    int s_l = (lane < cnt) ? csrSrc[base + lane] : 0;
    int i = 0;
    for (; i + 2 <= cnt; i += 2) {
      int s0 = __shfl(s_l, i);
      int s1 = __shfl(s_l, i + 1);
      float w0 = eeCsr[(size_t)(base + i) * H_ + head];
      float w1 = eeCsr[(size_t)(base + i + 1) * H_ + head];
      if (FPL == 4) {
        ushort4 r0 = ((const ushort4*)(h16 + (size_t)s0 * HC_))[lane];
        ushort4 r1 = ((const ushort4*)(h16 + (size_t)s1 * HC_))[lane];
        wsum += w0 + w1;
        acc[0] = fmaf(w0, bf2f(r0.x), acc[0]);
        acc[1] = fmaf(w0, bf2f(r0.y), acc[1]);
        acc[2] = fmaf(w0, bf2f(r0.z), acc[2]);
        acc[3] = fmaf(w0, bf2f(r0.w), acc[3]);
        acc[0] = fmaf(w1, bf2f(r1.x), acc[0]);
        acc[1] = fmaf(w1, bf2f(r1.y), acc[1]);
        acc[2] = fmaf(w1, bf2f(r1.z), acc[2]);
        acc[3] = fmaf(w1, bf2f(r1.w), acc[3]);
      } else {
        unsigned short r0 = h16[(size_t)s0 * HC_ + lane];
        unsigned short r1 = h16[(size_t)s1 * HC_ + lane];
        wsum += w0 + w1;
        acc[0] = fmaf(w0, bf2f(r0), acc[0]);
        acc[0] = fmaf(w1, bf2f(r1), acc[0]);
      }
    }
    if (i < cnt) {
      int s0 = __shfl(s_l, i);
      float w0 = eeCsr[(size_t)(base + i) * H_ + head];
      wsum += w0;
      if (FPL == 4) {
        ushort4 r0 = ((const ushort4*)(h16 + (size_t)s0 * HC_))[lane];
        acc[0] = fmaf(w0, bf2f(r0.x), acc[0]);
        acc[1] = fmaf(w0, bf2f(r0.y), acc[1]);
        acc[2] = fmaf(w0, bf2f(r0.z), acc[2]);
        acc[3] = fmaf(w0, bf2f(r0.w), acc[3]);
      } else {
        unsigned short r0 = h16[(size_t)s0 * HC_ + lane];
        acc[0] = fmaf(w0, bf2f(r0), acc[0]);
      }
    }
  }

  float inv = 1.0f / wsum;
  if (FPL == 4) {
    float4 o;
    o.x = acc[0] * inv; o.y = acc[1] * inv; o.z = acc[2] * inv; o.w = acc[3] * inv;
    if (bias) {
      const float4 b = ((const float4*)bias)[lane];
      o.x += b.x; o.y += b.y; o.z += b.z; o.w += b.w;
    }
    if (doElu) {
      o.x = o.x > 0.f ? o.x : expm1f(o.x);
      o.y = o.y > 0.f ? o.y : expm1f(o.y);
      o.z = o.z > 0.f ? o.z : expm1f(o.z);
      o.w = o.w > 0.f ? o.w : expm1f(o.w);
    }
    ((float4*)(outp + (size_t)wid * HC_))[lane] = o;
  } else {
    float o = acc[0] * inv;
    if (bias) o += bias[lane];
    if (doElu) o = o > 0.f ? o : expm1f(o);
    outp[(size_t)wid * HC_ + lane] = o;
  }
}

// ---------------- batch norm ----------------
__global__ void bn_stats_kernel(const float* __restrict__ x, int N,
                                float* __restrict__ sums, float* __restrict__ sumsq)
{
  int f = threadIdx.x;  // 256 columns
  int rpb = (N + gridDim.x - 1) / gridDim.x;
  int r0 = blockIdx.x * rpb;
  int r1 = min(N, r0 + rpb);
  float s = 0.f, q = 0.f;
  for (int r = r0; r < r1; ++r) {
    float v = x[(size_t)r * 256 + f];
    s += v; q += v * v;
  }
  atomicAdd(&sums[f], s);
  atomicAdd(&sumsq[f], q);
}

__global__ void bn_final_kernel(const float* __restrict__ sums, const float* __restrict__ sumsq,
                                const float* __restrict__ g, const float* __restrict__ be,
                                int N, float* __restrict__ scale, float* __restrict__ shift)
{
  int f = threadIdx.x;
  float mu = sums[f] / N;
  float var = sumsq[f] / N - mu * mu;
  float rs = rsqrtf(var + 1e-5f);
  float sc = g[f] * rs;
  scale[f] = sc;
  shift[f] = be[f] - mu * sc;
}

__global__ void bn_apply_elu_kernel(float* __restrict__ x, const float* __restrict__ scale,
                                    const float* __restrict__ shift, size_t n4)
{
  size_t i0 = (size_t)blockIdx.x * 256 + threadIdx.x;
  size_t stride = (size_t)gridDim.x * 256;
  for (size_t idx = i0; idx < n4; idx += stride) {
    float4 v = ((const float4*)x)[idx];
    int f = (int)((idx * 4) & 255);
    v.x = v.x * scale[f + 0] + shift[f + 0];
    v.y = v.y * scale[f + 1] + shift[f + 1];
    v.z = v.z * scale[f + 2] + shift[f + 2];
    v.w = v.w * scale[f + 3] + shift[f + 3];
    v.x = v.x > 0.f ? v.x : expm1f(v.x);
    v.y = v.y > 0.f ? v.y : expm1f(v.y);
    v.z = v.z > 0.f ? v.z : expm1f(v.z);
    v.w = v.w > 0.f ? v.w : expm1f(v.w);
    ((float4*)x)[idx] = v;
  }
}

// ---------------- MLP head ----------------
__global__ __launch_bounds__(256) void mlp_kernel(const float* __restrict__ h,
                           const float* __restrict__ fw1,
                           const float* __restrict__ fb1, const float* __restrict__ fw2,
                           const float* __restrict__ fb2, float* __restrict__ out, int N)
{
  const int lane = threadIdx.x & 63;
  const int j = lane & 31;        // hidden unit owned by this lane
  const int col = lane >> 5;      // output column (0 or 1)
  float w1c[64];
#pragma unroll
  for (int k = 0; k < 64; ++k) w1c[k] = fw1[k * 32 + j];
  const float b1v = fb1[j];
  const float w2v = fw2[j * 2 + col];
  const float b2v = fb2[col];

  const int nwaves = (int)(gridDim.x * (blockDim.x >> 6));
  int wid = (int)(blockIdx.x * (blockDim.x >> 6) + (threadIdx.x >> 6));
  for (int n = wid; n < N; n += nwaves) {
    float hv = h[(size_t)n * 64 + lane];
    float acc = 0.f;
#pragma unroll
    for (int k = 0; k < 64; ++k) {
      float s = __shfl(hv, k);
      acc = fmaf(s, w1c[k], acc);
    }
    float hid = fmaxf(acc + b1v, 0.f);
    float p = hid * w2v;
#pragma unroll
    for (int off = 16; off; off >>= 1) p += __shfl_xor(p, off);
    if (j == 0) out[(size_t)n * 2 + col] = p + b2v;
  }
}

// ---------------- host ----------------
extern "C" void kernel_launch(void* const* d_in, const int* in_sizes, int n_in,
                              void* d_out, int out_size, void* d_ws, size_t ws_size,
                              hipStream_t stream)
{
  const float* x   = (const float*)d_in[0];
  const int*   ei  = (const int*)d_in[1];
  const float* W1  = (const float*)d_in[2];
  const float* a1s = (const float*)d_in[3];
  const float* a1d = (const float*)d_in[4];
  const float* W2  = (const float*)d_in[6];
  const float* a2s = (const float*)d_in[7];
  const float* a2d = (const float*)d_in[8];
  const float* W3  = (const float*)d_in[10];
  const float* a3s = (const float*)d_in[11];
  const float* a3d = (const float*)d_in[12];
  const float* b3  = (const float*)d_in[13];
  const float* g1  = (const float*)d_in[14];
  const float* be1 = (const float*)d_in[15];
  const float* g2  = (const float*)d_in[16];
  const float* be2 = (const float*)d_in[17];
  const float* fw1 = (const float*)d_in[18];
  const float* fb1 = (const float*)d_in[19];
  const float* fw2 = (const float*)d_in[20];
  const float* fb2 = (const float*)d_in[21];
  float* out = (float*)d_out;

  const int F = 128;
  const int N = in_sizes[0] / F;
  const int E = in_sizes[1] / 2;
  const int Etot = E + N;
  const int* srcIdx = ei;
  const int* dstIdx = ei + E;

  // workspace layout (256B aligned slices)
  char* w = (char*)d_ws;
  auto alloc = [&](size_t bytes) -> void* {
    void* p = (void*)w;
    w += (bytes + 255) & ~(size_t)255;
    return p;
  };
  unsigned short* h16 = (unsigned short*)alloc((size_t)N * 256 * 2);
  float* act     = (float*)alloc((size_t)N * 256 * 4);
  float* eeCsr   = (float*)alloc((size_t)Etot * 4 * 4);
  float* als     = (float*)alloc((size_t)N * 4 * 4);
  float* ald     = (float*)alloc((size_t)N * 4 * 4);
  int*   counts  = (int*)alloc((size_t)N * 4);
  int*   cursor  = (int*)alloc((size_t)N * 4);
  int*   rowStart= (int*)alloc((size_t)(N + 1) * 4);
  int*   csrSrc  = (int*)alloc((size_t)Etot * 4);
  int*   csrDst  = (int*)alloc((size_t)Etot * 4);
  int*   bsums   = (int*)alloc((size_t)((N + 255) / 256) * 4);
  float* sums    = (float*)alloc(256 * 4);
  float* sumsq   = (float*)alloc(256 * 4);
  float* scale   = (float*)alloc(256 * 4);
  float* shift   = (float*)alloc(256 * 4);

  const int nb = (N + 255) / 256;
  const int ebk = (Etot + 255) / 256;
  const int aggBlocks = (N + 3) / 4;

  // ---- CSR build (reused by all 3 layers) ----
  hipMemsetAsync(counts, 0, (size_t)N * 4, stream);
  hipMemsetAsync(cursor, 0, (size_t)N * 4, stream);
  count_kernel<<<ebk, 256, 0, stream>>>(dstIdx, E, Etot, counts);
  block_sum_kernel<<<nb, 256, 0, stream>>>(counts, N, bsums);
  scan_bsums_kernel<<<1, 1, 0, stream>>>(bsums, nb);
  scan_write_kernel<<<nb, 256, 0, stream>>>(counts, N, bsums, rowStart, Etot);
  fill_kernel<<<ebk, 256, 0, stream>>>(srcIdx, dstIdx, E, Etot, rowStart, cursor, csrSrc, csrDst);

  dim3 gemm_grid2((N + 127) / 128, 2);
  dim3 gemm_grid1((N + 127) / 128, 1);

  // ---- GAT layer 1: x[N,128] -> act[N,256] (bias cancels in BN) ----
  gemm_kernel<2><<<gemm_grid2, 256, 0, stream>>>(x, W1, h16, N, 256, F);
  al_kernel<4><<<N, 256, 0, stream>>>(h16, a1s, a1d, als, ald, N);
  edge_kernel<4><<<(Etot * 4 + 255) / 256, 256, 0, stream>>>(csrSrc, csrDst, Etot, als, ald, eeCsr);
  aggregate_kernel<256><<<aggBlocks, 256, 0, stream>>>(h16, eeCsr, csrSrc, rowStart, act, N, nullptr, 0);
  // BN1 + ELU (in place on act)
  hipMemsetAsync(sums, 0, 256 * 4, stream);
  hipMemsetAsync(sumsq, 0, 256 * 4, stream);
  bn_stats_kernel<<<128, 256, 0, stream>>>(act, N, sums, sumsq);
  bn_final_kernel<<<1, 256, 0, stream>>>(sums, sumsq, g1, be1, N, scale, shift);
  bn_apply_elu_kernel<<<1024, 256, 0, stream>>>(act, scale, shift, (size_t)N * 64);

  // ---- GAT layer 2: act[N,256] -> act[N,256] ----
  gemm_kernel<2><<<gemm_grid2, 256, 0, stream>>>(act, W2, h16, N, 256, 256);
  al_kernel<4><<<N, 256, 0, stream>>>(h16, a2s, a2d, als, ald, N);
  edge_kernel<4><<<(Etot * 4 + 255) / 256, 256, 0, stream>>>(csrSrc, csrDst, Etot, als, ald, eeCsr);
  aggregate_kernel<256><<<aggBlocks, 256, 0, stream>>>(h16, eeCsr, csrSrc, rowStart, act, N, nullptr, 0);
  // BN2 + ELU
  hipMemsetAsync(sums, 0, 256 * 4, stream);
  hipMemsetAsync(sumsq, 0, 256 * 4, stream);
  bn_stats_kernel<<<128, 256, 0, stream>>>(act, N, sums, sumsq);
  bn_final_kernel<<<1, 256, 0, stream>>>(sums, sumsq, g2, be2, N, scale, shift);
  bn_apply_elu_kernel<<<1024, 256, 0, stream>>>(act, scale, shift, (size_t)N * 64);

  // ---- GAT layer 3 (1 head, C=64): act[N,256] -> act[N,64] with +b3, ELU ----
  gemm_kernel<1><<<gemm_grid1, 256, 0, stream>>>(act, W3, h16, N, 64, 256);
  al_kernel<1><<<N, 64, 0, stream>>>(h16, a3s, a3d, als, ald, N);
  edge_kernel<1><<<(Etot + 255) / 256, 256, 0, stream>>>(csrSrc, csrDst, Etot, als, ald, eeCsr);
  aggregate_kernel<64><<<aggBlocks, 256, 0, stream>>>(h16, eeCsr, csrSrc, rowStart, act, N, b3, 1);

  // ---- MLP head ----
  mlp_kernel<<<1024, 256, 0, stream>>>(act, fw1, fb1, fw2, fb2, out, N);
}

// Round 4
// 667.319 us; speedup vs baseline: 1.7864x; 1.1156x over previous
//
#include <hip/hip_runtime.h>
#include <math.h>
#include <stdint.h>

typedef __attribute__((ext_vector_type(8))) short short8v;
typedef __attribute__((ext_vector_type(4))) float float4v;

// ---------------- utility ----------------
__device__ __forceinline__ float warp_sum64(float v) {
#pragma unroll
  for (int off = 32; off; off >>= 1) v += __shfl_xor(v, off);
  return v;
}

__device__ __forceinline__ float bf2f(unsigned short u) {
  return __uint_as_float((unsigned int)u << 16);
}
__device__ __forceinline__ unsigned short f2bf(float f) {   // RNE
  unsigned int u = __float_as_uint(f);
  unsigned int r = (u + 0x7FFFu + ((u >> 16) & 1u)) >> 16;
  return (unsigned short)r;
}

// ---------------- weight prep: fp32 W[K][Nw] -> hi/lo bf16 in MFMA-frag order ----
// frag_id = n_tile*(K/32)+k_tile; elem index = (frag_id*64+lane)*8+i
// element: k = k_tile*32 + 8*(lane>>4) + i ; n = n_tile*16 + (lane&15)
__global__ void wprep_kernel(const float* __restrict__ W, unsigned short* __restrict__ Wh,
                             unsigned short* __restrict__ Wl, int K, int Nw)
{
  int t = blockIdx.x * 256 + threadIdx.x;
  if (t >= K * Nw) return;
  int i = t & 7;
  int lane = (t >> 3) & 63;
  int frag = t >> 9;
  int ktiles = K >> 5;
  int n_tile = frag / ktiles, k_tile = frag - n_tile * ktiles;
  int k = k_tile * 32 + ((lane >> 4) << 3) + i;
  int n = (n_tile << 4) + (lane & 15);
  float v = W[(size_t)k * Nw + n];
  unsigned short hi = (unsigned short)(__float_as_uint(v) >> 16);   // trunc
  float rem = v - bf2f(hi);
  Wh[t] = hi;
  Wl[t] = f2bf(rem);
}

// ---------------- MFMA GEMM: C[M,Nw](bf16) = A[M,K](f32) @ B ----------------
// B pre-split hi/lo in frag order. Optional fused BN(scale,shift)+ELU on A.
// 4 waves; wave grid WM x WN (WM*WN==4); each wave computes 64x64.
template<int WM, int WN, bool FUSE>
__global__ __launch_bounds__(256) void gemm_mfma(const float* __restrict__ A,
    const unsigned short* __restrict__ Bh, const unsigned short* __restrict__ Bl,
    const float* __restrict__ scale, const float* __restrict__ shift,
    unsigned short* __restrict__ C, int M, int Nw, int K)
{
  constexpr int BM = WM * 64, BN = WN * 64;
  const int wid = threadIdx.x >> 6, lane = threadIdx.x & 63;
  const int wm = wid / WN, wn = wid % WN;
  const int m0 = blockIdx.x * BM + wm * 64;
  const int n0 = blockIdx.y * BN + wn * 64;
  const int ar = lane & 15;
  const int kb = (lane >> 4) << 3;
  const int ktiles = K >> 5;
  const int ntile0 = n0 >> 4;

  float4v acc[4][4];
#pragma unroll
  for (int mi = 0; mi < 4; ++mi)
#pragma unroll
    for (int ni = 0; ni < 4; ++ni)
      acc[mi][ni] = (float4v){0.f, 0.f, 0.f, 0.f};

  for (int kt = 0; kt < ktiles; ++kt) {
    const int kk = kt * 32 + kb;
    // B fragments: 16B loads, L2-resident
    short8v bh[4], bl[4];
#pragma unroll
    for (int ni = 0; ni < 4; ++ni) {
      size_t off = (((size_t)(ntile0 + ni) * ktiles + kt) * 64 + lane) * 8;
      bh[ni] = *(const short8v*)(Bh + off);
      bl[ni] = *(const short8v*)(Bl + off);
    }
    // A raw floats (2x float4 per m-subtile)
    float4 ra0[4], ra1[4];
#pragma unroll
    for (int mi = 0; mi < 4; ++mi) {
      int row = m0 + mi * 16 + ar;
      if (row < M) {
        const float* p = A + (size_t)row * K + kk;
        ra0[mi] = *(const float4*)p;
        ra1[mi] = *(const float4*)(p + 4);
      } else {
        ra0[mi] = make_float4(0.f, 0.f, 0.f, 0.f);
        ra1[mi] = make_float4(0.f, 0.f, 0.f, 0.f);
      }
    }
    float4 sc0, sc1, sh0, sh1;
    if (FUSE) {
      sc0 = *(const float4*)(scale + kk); sc1 = *(const float4*)(scale + kk + 4);
      sh0 = *(const float4*)(shift + kk); sh1 = *(const float4*)(shift + kk + 4);
    }
    // convert to hi/lo bf16 fragments
    short8v ah[4], al_[4];
#pragma unroll
    for (int mi = 0; mi < 4; ++mi) {
      float v[8];
      v[0] = ra0[mi].x; v[1] = ra0[mi].y; v[2] = ra0[mi].z; v[3] = ra0[mi].w;
      v[4] = ra1[mi].x; v[5] = ra1[mi].y; v[6] = ra1[mi].z; v[7] = ra1[mi].w;
      if (FUSE) {
        float sc[8] = {sc0.x, sc0.y, sc0.z, sc0.w, sc1.x, sc1.y, sc1.z, sc1.w};
        float sh[8] = {sh0.x, sh0.y, sh0.z, sh0.w, sh1.x, sh1.y, sh1.z, sh1.w};
#pragma unroll
        for (int j = 0; j < 8; ++j) {
          float t = fmaf(v[j], sc[j], sh[j]);
          v[j] = t > 0.f ? t : expm1f(t);     // ELU
        }
      }
#pragma unroll
      for (int j = 0; j < 8; ++j) {
        unsigned int ub = __float_as_uint(v[j]);
        unsigned short h = (unsigned short)(ub >> 16);       // trunc hi
        float rem = v[j] - __uint_as_float((unsigned int)h << 16);
        ah[mi][j] = (short)h;
        al_[mi][j] = (short)f2bf(rem);
      }
    }
    // split-3 MFMA: Ah*Bh + Ah*Bl + Al*Bh  (~fp32 accuracy)
#pragma unroll
    for (int mi = 0; mi < 4; ++mi)
#pragma unroll
      for (int ni = 0; ni < 4; ++ni) {
        acc[mi][ni] = __builtin_amdgcn_mfma_f32_16x16x32_bf16(ah[mi], bh[ni], acc[mi][ni], 0, 0, 0);
        acc[mi][ni] = __builtin_amdgcn_mfma_f32_16x16x32_bf16(ah[mi], bl[ni], acc[mi][ni], 0, 0, 0);
        acc[mi][ni] = __builtin_amdgcn_mfma_f32_16x16x32_bf16(al_[mi], bh[ni], acc[mi][ni], 0, 0, 0);
      }
  }
  // epilogue: D lane mapping col=lane&15, row=(lane>>4)*4+r
  const int cc = lane & 15;
#pragma unroll
  for (int mi = 0; mi < 4; ++mi) {
    int rowb = m0 + mi * 16 + ((lane >> 4) << 2);
#pragma unroll
    for (int r = 0; r < 4; ++r) {
      int row = rowb + r;
      if (row < M) {
#pragma unroll
        for (int ni = 0; ni < 4; ++ni)
          C[(size_t)row * Nw + n0 + ni * 16 + cc] = f2bf(acc[mi][ni][r]);
      }
    }
  }
}

// ---------------- attention logits from bf16 h ----------------
template<int H>
__global__ void al_kernel(const unsigned short* __restrict__ h, const float* __restrict__ a_s,
                          const float* __restrict__ a_d, float* __restrict__ al_s,
                          float* __restrict__ al_d, int N)
{
  int n = blockIdx.x;
  int tid = threadIdx.x;
  int hh = tid >> 6, lane = tid & 63;
  float hv = bf2f(h[(size_t)n * (H * 64) + tid]);
  float ps = hv * a_s[tid];
  float pd = hv * a_d[tid];
  ps = warp_sum64(ps);
  pd = warp_sum64(pd);
  if (lane == 0) { al_s[n * H + hh] = ps; al_d[n * H + hh] = pd; }
}

// ---------------- per-position exp(leaky_relu), CSR order, no atomics ----------------
template<int H>
__global__ void edge_kernel(const int* __restrict__ csrSrc, const int* __restrict__ csrDst,
                            int Etot, const float* __restrict__ al_s,
                            const float* __restrict__ al_d, float* __restrict__ eeCsr)
{
  int t = blockIdx.x * 256 + threadIdx.x;
  if (t >= Etot * H) return;
  int pos = t / H, hh = t - pos * H;
  int s = csrSrc[pos], d = csrDst[pos];
  float x = al_s[s * H + hh] + al_d[d * H + hh];
  x = x > 0.f ? x : 0.2f * x;           // leaky_relu(0.2)
  eeCsr[t] = expf(x);                    // softmax shift-invariant: skip segment max
}

// ---------------- CSR build ----------------
__global__ void count_kernel(const int* __restrict__ dst, int E, int Etot, int* __restrict__ counts)
{
  int e = blockIdx.x * 256 + threadIdx.x;
  if (e >= Etot) return;
  int d = (e < E) ? dst[e] : (e - E);
  atomicAdd(&counts[d], 1);
}

__global__ void block_sum_kernel(const int* __restrict__ counts, int N, int* __restrict__ bsums)
{
  __shared__ int sd[256];
  int i = blockIdx.x * 256 + threadIdx.x;
  sd[threadIdx.x] = (i < N) ? counts[i] : 0;
  __syncthreads();
  for (int off = 128; off; off >>= 1) {
    if (threadIdx.x < off) sd[threadIdx.x] += sd[threadIdx.x + off];
    __syncthreads();
  }
  if (threadIdx.x == 0) bsums[blockIdx.x] = sd[0];
}

__global__ void scan_bsums_kernel(int* bsums, int nb)
{
  if (blockIdx.x == 0 && threadIdx.x == 0) {
    int run = 0;
    for (int i = 0; i < nb; ++i) { int v = bsums[i]; bsums[i] = run; run += v; }
  }
}

__global__ void scan_write_kernel(const int* __restrict__ counts, int N,
                                  const int* __restrict__ bsums, int* __restrict__ rowStart, int Etot)
{
  __shared__ int sd[256];
  int i = blockIdx.x * 256 + threadIdx.x;
  int v = (i < N) ? counts[i] : 0;
  sd[threadIdx.x] = v;
  __syncthreads();
  for (int off = 1; off < 256; off <<= 1) {
    int x = (threadIdx.x >= off) ? sd[threadIdx.x - off] : 0;
    __syncthreads();
    sd[threadIdx.x] += x;
    __syncthreads();
  }
  if (i < N) rowStart[i] = bsums[blockIdx.x] + sd[threadIdx.x] - v;  // exclusive
  if (i == N - 1) rowStart[N] = Etot;
}

__global__ void fill_kernel(const int* __restrict__ src, const int* __restrict__ dst,
                            int E, int Etot, const int* __restrict__ rowStart,
                            int* __restrict__ cursor, int* __restrict__ csrSrc,
                            int* __restrict__ csrDst)
{
  int e = blockIdx.x * 256 + threadIdx.x;
  if (e >= Etot) return;
  int s, d;
  if (e < E) { s = src[e]; d = dst[e]; } else { s = d = e - E; }
  int pos = rowStart[d] + atomicAdd(&cursor[d], 1);
  csrSrc[pos] = s;
  csrDst[pos] = d;
}

// ---------------- aggregation: wave per node, bf16 gather, inline denom ----------------
template<int HC_>
__global__ __launch_bounds__(256) void aggregate_kernel(
    const unsigned short* __restrict__ h16, const float* __restrict__ eeCsr,
    const int* __restrict__ csrSrc, const int* __restrict__ rowStart,
    float* __restrict__ outp, int N, const float* __restrict__ bias, int doElu)
{
  constexpr int H_ = HC_ / 64;       // heads (4 or 1)
  constexpr int FPL = HC_ / 64;      // features per lane (4 or 1)
  int wid = (int)(blockIdx.x * (blockDim.x >> 6) + (threadIdx.x >> 6));
  if (wid >= N) return;
  const int lane = threadIdx.x & 63;
  const int head = (H_ == 4) ? (lane >> 4) : 0;
  const int start = rowStart[wid], end = rowStart[wid + 1];

  float acc[FPL] = {};
  float wsum = 0.f;

  for (int base = start; base < end; base += 64) {
    int cnt = end - base; if (cnt > 64) cnt = 64;
    int s_l = (lane < cnt) ? csrSrc[base + lane] : 0;
    int i = 0;
    for (; i + 2 <= cnt; i += 2) {
      int s0 = __shfl(s_l, i);
      int s1 = __shfl(s_l, i + 1);
      float w0 = eeCsr[(size_t)(base + i) * H_ + head];
      float w1 = eeCsr[(size_t)(base + i + 1) * H_ + head];
      if (FPL == 4) {
        ushort4 r0 = ((const ushort4*)(h16 + (size_t)s0 * HC_))[lane];
        ushort4 r1 = ((const ushort4*)(h16 + (size_t)s1 * HC_))[lane];
        wsum += w0 + w1;
        acc[0] = fmaf(w0, bf2f(r0.x), acc[0]);
        acc[1] = fmaf(w0, bf2f(r0.y), acc[1]);
        acc[2] = fmaf(w0, bf2f(r0.z), acc[2]);
        acc[3] = fmaf(w0, bf2f(r0.w), acc[3]);
        acc[0] = fmaf(w1, bf2f(r1.x), acc[0]);
        acc[1] = fmaf(w1, bf2f(r1.y), acc[1]);
        acc[2] = fmaf(w1, bf2f(r1.z), acc[2]);
        acc[3] = fmaf(w1, bf2f(r1.w), acc[3]);
      } else {
        unsigned short r0 = h16[(size_t)s0 * HC_ + lane];
        unsigned short r1 = h16[(size_t)s1 * HC_ + lane];
        wsum += w0 + w1;
        acc[0] = fmaf(w0, bf2f(r0), acc[0]);
        acc[0] = fmaf(w1, bf2f(r1), acc[0]);
      }
    }
    if (i < cnt) {
      int s0 = __shfl(s_l, i);
      float w0 = eeCsr[(size_t)(base + i) * H_ + head];
      wsum += w0;
      if (FPL == 4) {
        ushort4 r0 = ((const ushort4*)(h16 + (size_t)s0 * HC_))[lane];
        acc[0] = fmaf(w0, bf2f(r0.x), acc[0]);
        acc[1] = fmaf(w0, bf2f(r0.y), acc[1]);
        acc[2] = fmaf(w0, bf2f(r0.z), acc[2]);
        acc[3] = fmaf(w0, bf2f(r0.w), acc[3]);
      } else {
        unsigned short r0 = h16[(size_t)s0 * HC_ + lane];
        acc[0] = fmaf(w0, bf2f(r0), acc[0]);
      }
    }
  }

  float inv = 1.0f / wsum;
  if (FPL == 4) {
    float4 o;
    o.x = acc[0] * inv; o.y = acc[1] * inv; o.z = acc[2] * inv; o.w = acc[3] * inv;
    if (bias) {
      const float4 b = ((const float4*)bias)[lane];
      o.x += b.x; o.y += b.y; o.z += b.z; o.w += b.w;
    }
    if (doElu) {
      o.x = o.x > 0.f ? o.x : expm1f(o.x);
      o.y = o.y > 0.f ? o.y : expm1f(o.y);
      o.z = o.z > 0.f ? o.z : expm1f(o.z);
      o.w = o.w > 0.f ? o.w : expm1f(o.w);
    }
    ((float4*)(outp + (size_t)wid * HC_))[lane] = o;
  } else {
    float o = acc[0] * inv;
    if (bias) o += bias[lane];
    if (doElu) o = o > 0.f ? o : expm1f(o);
    outp[(size_t)wid * HC_ + lane] = o;
  }
}

// ---------------- batch norm stats ----------------
__global__ void bn_stats_kernel(const float* __restrict__ x, int N,
                                float* __restrict__ sums, float* __restrict__ sumsq)
{
  int f = threadIdx.x;  // 256 columns
  int rpb = (N + gridDim.x - 1) / gridDim.x;
  int r0 = blockIdx.x * rpb;
  int r1 = min(N, r0 + rpb);
  float s = 0.f, q = 0.f;
  for (int r = r0; r < r1; ++r) {
    float v = x[(size_t)r * 256 + f];
    s += v; q += v * v;
  }
  atomicAdd(&sums[f], s);
  atomicAdd(&sumsq[f], q);
}

__global__ void bn_final_kernel(const float* __restrict__ sums, const float* __restrict__ sumsq,
                                const float* __restrict__ g, const float* __restrict__ be,
                                int N, float* __restrict__ scale, float* __restrict__ shift)
{
  int f = threadIdx.x;
  float mu = sums[f] / N;
  float var = sumsq[f] / N - mu * mu;
  float rs = rsqrtf(var + 1e-5f);
  float sc = g[f] * rs;
  scale[f] = sc;
  shift[f] = be[f] - mu * sc;
}

// ---------------- MLP head ----------------
__global__ __launch_bounds__(256) void mlp_kernel(const float* __restrict__ h,
                           const float* __restrict__ fw1,
                           const float* __restrict__ fb1, const float* __restrict__ fw2,
                           const float* __restrict__ fb2, float* __restrict__ out, int N)
{
  const int lane = threadIdx.x & 63;
  const int j = lane & 31;
  const int col = lane >> 5;
  float w1c[64];
#pragma unroll
  for (int k = 0; k < 64; ++k) w1c[k] = fw1[k * 32 + j];
  const float b1v = fb1[j];
  const float w2v = fw2[j * 2 + col];
  const float b2v = fb2[col];

  const int nwaves = (int)(gridDim.x * (blockDim.x >> 6));
  int wid = (int)(blockIdx.x * (blockDim.x >> 6) + (threadIdx.x >> 6));
  for (int n = wid; n < N; n += nwaves) {
    float hv = h[(size_t)n * 64 + lane];
    float acc = 0.f;
#pragma unroll
    for (int k = 0; k < 64; ++k) {
      float s = __shfl(hv, k);
      acc = fmaf(s, w1c[k], acc);
    }
    float hid = fmaxf(acc + b1v, 0.f);
    float p = hid * w2v;
#pragma unroll
    for (int off = 16; off; off >>= 1) p += __shfl_xor(p, off);
    if (j == 0) out[(size_t)n * 2 + col] = p + b2v;
  }
}

// ---------------- host ----------------
extern "C" void kernel_launch(void* const* d_in, const int* in_sizes, int n_in,
                              void* d_out, int out_size, void* d_ws, size_t ws_size,
                              hipStream_t stream)
{
  const float* x   = (const float*)d_in[0];
  const int*   ei  = (const int*)d_in[1];
  const float* W1  = (const float*)d_in[2];
  const float* a1s = (const float*)d_in[3];
  const float* a1d = (const float*)d_in[4];
  const float* W2  = (const float*)d_in[6];
  const float* a2s = (const float*)d_in[7];
  const float* a2d = (const float*)d_in[8];
  const float* W3  = (const float*)d_in[10];
  const float* a3s = (const float*)d_in[11];
  const float* a3d = (const float*)d_in[12];
  const float* b3  = (const float*)d_in[13];
  const float* g1  = (const float*)d_in[14];
  const float* be1 = (const float*)d_in[15];
  const float* g2  = (const float*)d_in[16];
  const float* be2 = (const float*)d_in[17];
  const float* fw1 = (const float*)d_in[18];
  const float* fb1 = (const float*)d_in[19];
  const float* fw2 = (const float*)d_in[20];
  const float* fb2 = (const float*)d_in[21];
  float* out = (float*)d_out;

  const int F = 128;
  const int N = in_sizes[0] / F;
  const int E = in_sizes[1] / 2;
  const int Etot = E + N;
  const int* srcIdx = ei;
  const int* dstIdx = ei + E;

  // workspace layout (256B aligned slices)
  char* w = (char*)d_ws;
  auto alloc = [&](size_t bytes) -> void* {
    void* p = (void*)w;
    w += (bytes + 255) & ~(size_t)255;
    return p;
  };
  unsigned short* h16 = (unsigned short*)alloc((size_t)N * 256 * 2);
  float* act     = (float*)alloc((size_t)N * 256 * 4);
  float* eeCsr   = (float*)alloc((size_t)Etot * 4 * 4);
  float* als     = (float*)alloc((size_t)N * 4 * 4);
  float* ald     = (float*)alloc((size_t)N * 4 * 4);
  int*   counts  = (int*)alloc((size_t)N * 4);
  int*   cursor  = (int*)alloc((size_t)N * 4);
  int*   rowStart= (int*)alloc((size_t)(N + 1) * 4);
  int*   csrSrc  = (int*)alloc((size_t)Etot * 4);
  int*   csrDst  = (int*)alloc((size_t)Etot * 4);
  int*   bsums   = (int*)alloc((size_t)((N + 255) / 256) * 4);
  float* sums    = (float*)alloc(256 * 4);
  float* sumsq   = (float*)alloc(256 * 4);
  float* scale1  = (float*)alloc(256 * 4);
  float* shift1  = (float*)alloc(256 * 4);
  float* scale2  = (float*)alloc(256 * 4);
  float* shift2  = (float*)alloc(256 * 4);
  unsigned short* w1h = (unsigned short*)alloc((size_t)128 * 256 * 2);
  unsigned short* w1l = (unsigned short*)alloc((size_t)128 * 256 * 2);
  unsigned short* w2h = (unsigned short*)alloc((size_t)256 * 256 * 2);
  unsigned short* w2l = (unsigned short*)alloc((size_t)256 * 256 * 2);
  unsigned short* w3h = (unsigned short*)alloc((size_t)256 * 64 * 2);
  unsigned short* w3l = (unsigned short*)alloc((size_t)256 * 64 * 2);

  const int nb = (N + 255) / 256;
  const int ebk = (Etot + 255) / 256;
  const int aggBlocks = (N + 3) / 4;

  // ---- weight prep (frag-ordered bf16 hi/lo) ----
  wprep_kernel<<<(128 * 256 + 255) / 256, 256, 0, stream>>>(W1, w1h, w1l, 128, 256);
  wprep_kernel<<<(256 * 256 + 255) / 256, 256, 0, stream>>>(W2, w2h, w2l, 256, 256);
  wprep_kernel<<<(256 * 64 + 255) / 256, 256, 0, stream>>>(W3, w3h, w3l, 256, 64);

  // ---- CSR build (reused by all 3 layers) ----
  hipMemsetAsync(counts, 0, (size_t)N * 4, stream);
  hipMemsetAsync(cursor, 0, (size_t)N * 4, stream);
  count_kernel<<<ebk, 256, 0, stream>>>(dstIdx, E, Etot, counts);
  block_sum_kernel<<<nb, 256, 0, stream>>>(counts, N, bsums);
  scan_bsums_kernel<<<1, 1, 0, stream>>>(bsums, nb);
  scan_write_kernel<<<nb, 256, 0, stream>>>(counts, N, bsums, rowStart, Etot);
  fill_kernel<<<ebk, 256, 0, stream>>>(srcIdx, dstIdx, E, Etot, rowStart, cursor, csrSrc, csrDst);

  dim3 g12((N + 127) / 128, 2);   // layers 1,2: BM=128, BN=128, N=256
  dim3 g3((N + 255) / 256, 1);    // layer 3: BM=256, BN=64

  // ---- GAT layer 1: x[N,128] -> act[N,256] (bias cancels in BN) ----
  gemm_mfma<2, 2, false><<<g12, 256, 0, stream>>>(x, w1h, w1l, nullptr, nullptr, h16, N, 256, 128);
  al_kernel<4><<<N, 256, 0, stream>>>(h16, a1s, a1d, als, ald, N);
  edge_kernel<4><<<(Etot * 4 + 255) / 256, 256, 0, stream>>>(csrSrc, csrDst, Etot, als, ald, eeCsr);
  aggregate_kernel<256><<<aggBlocks, 256, 0, stream>>>(h16, eeCsr, csrSrc, rowStart, act, N, nullptr, 0);
  // BN1 stats -> scale1/shift1 (apply+ELU fused into next GEMM's A-load)
  hipMemsetAsync(sums, 0, 256 * 4, stream);
  hipMemsetAsync(sumsq, 0, 256 * 4, stream);
  bn_stats_kernel<<<128, 256, 0, stream>>>(act, N, sums, sumsq);
  bn_final_kernel<<<1, 256, 0, stream>>>(sums, sumsq, g1, be1, N, scale1, shift1);

  // ---- GAT layer 2: elu(bn(act)) @ W2 -> h16 ----
  gemm_mfma<2, 2, true><<<g12, 256, 0, stream>>>(act, w2h, w2l, scale1, shift1, h16, N, 256, 256);
  al_kernel<4><<<N, 256, 0, stream>>>(h16, a2s, a2d, als, ald, N);
  edge_kernel<4><<<(Etot * 4 + 255) / 256, 256, 0, stream>>>(csrSrc, csrDst, Etot, als, ald, eeCsr);
  aggregate_kernel<256><<<aggBlocks, 256, 0, stream>>>(h16, eeCsr, csrSrc, rowStart, act, N, nullptr, 0);
  // BN2 stats -> scale2/shift2
  hipMemsetAsync(sums, 0, 256 * 4, stream);
  hipMemsetAsync(sumsq, 0, 256 * 4, stream);
  bn_stats_kernel<<<128, 256, 0, stream>>>(act, N, sums, sumsq);
  bn_final_kernel<<<1, 256, 0, stream>>>(sums, sumsq, g2, be2, N, scale2, shift2);

  // ---- GAT layer 3 (1 head, C=64): elu(bn(act)) @ W3 -> h16[N,64]; agg +b3, ELU ----
  gemm_mfma<4, 1, true><<<g3, 256, 0, stream>>>(act, w3h, w3l, scale2, shift2, h16, N, 64, 256);
  al_kernel<1><<<N, 64, 0, stream>>>(h16, a3s, a3d, als, ald, N);
  edge_kernel<1><<<(Etot + 255) / 256, 256, 0, stream>>>(csrSrc, csrDst, Etot, als, ald, eeCsr);
  aggregate_kernel<64><<<aggBlocks, 256, 0, stream>>>(h16, eeCsr, csrSrc, rowStart, act, N, b3, 1);

  // ---- MLP head ----
  mlp_kernel<<<1024, 256, 0, stream>>>(act, fw1, fb1, fw2, fb2, out, N);
}

// Round 5
// 500.874 us; speedup vs baseline: 2.3800x; 1.3323x over previous
//
#include <hip/hip_runtime.h>
#include <math.h>
#include <stdint.h>

typedef __attribute__((ext_vector_type(8))) short short8v;
typedef __attribute__((ext_vector_type(4))) float float4v;

// ---------------- utility ----------------
__device__ __forceinline__ float warp_sum64(float v) {
#pragma unroll
  for (int off = 32; off; off >>= 1) v += __shfl_xor(v, off);
  return v;
}

__device__ __forceinline__ float bf2f(unsigned short u) {
  return __uint_as_float((unsigned int)u << 16);
}
__device__ __forceinline__ unsigned short f2bf(float f) {   // RNE
  unsigned int u = __float_as_uint(f);
  unsigned int r = (u + 0x7FFFu + ((u >> 16) & 1u)) >> 16;
  return (unsigned short)r;
}

// ---------------- weight prep: fp32 W[K][Nw] -> hi/lo bf16 in MFMA-frag order ----
__global__ void wprep_kernel(const float* __restrict__ W, unsigned short* __restrict__ Wh,
                             unsigned short* __restrict__ Wl, int K, int Nw)
{
  int t = blockIdx.x * 256 + threadIdx.x;
  if (t >= K * Nw) return;
  int i = t & 7;
  int lane = (t >> 3) & 63;
  int frag = t >> 9;
  int ktiles = K >> 5;
  int n_tile = frag / ktiles, k_tile = frag - n_tile * ktiles;
  int k = k_tile * 32 + ((lane >> 4) << 3) + i;
  int n = (n_tile << 4) + (lane & 15);
  float v = W[(size_t)k * Nw + n];
  unsigned short hi = (unsigned short)(__float_as_uint(v) >> 16);   // trunc
  float rem = v - bf2f(hi);
  Wh[t] = hi;
  Wl[t] = f2bf(rem);
}

// ---------------- MFMA GEMM: C[M,Nw](bf16) = A[M,K](f32) @ B ----------------
template<int WM, int WN, bool FUSE>
__global__ __launch_bounds__(256) void gemm_mfma(const float* __restrict__ A,
    const unsigned short* __restrict__ Bh, const unsigned short* __restrict__ Bl,
    const float* __restrict__ scale, const float* __restrict__ shift,
    unsigned short* __restrict__ C, int M, int Nw, int K)
{
  constexpr int BM = WM * 64, BN = WN * 64;
  const int wid = threadIdx.x >> 6, lane = threadIdx.x & 63;
  const int wm = wid / WN, wn = wid % WN;
  const int m0 = blockIdx.x * BM + wm * 64;
  const int n0 = blockIdx.y * BN + wn * 64;
  const int ar = lane & 15;
  const int kb = (lane >> 4) << 3;
  const int ktiles = K >> 5;
  const int ntile0 = n0 >> 4;

  float4v acc[4][4];
#pragma unroll
  for (int mi = 0; mi < 4; ++mi)
#pragma unroll
    for (int ni = 0; ni < 4; ++ni)
      acc[mi][ni] = (float4v){0.f, 0.f, 0.f, 0.f};

  for (int kt = 0; kt < ktiles; ++kt) {
    const int kk = kt * 32 + kb;
    short8v bh[4], bl[4];
#pragma unroll
    for (int ni = 0; ni < 4; ++ni) {
      size_t off = (((size_t)(ntile0 + ni) * ktiles + kt) * 64 + lane) * 8;
      bh[ni] = *(const short8v*)(Bh + off);
      bl[ni] = *(const short8v*)(Bl + off);
    }
    float4 ra0[4], ra1[4];
#pragma unroll
    for (int mi = 0; mi < 4; ++mi) {
      int row = m0 + mi * 16 + ar;
      if (row < M) {
        const float* p = A + (size_t)row * K + kk;
        ra0[mi] = *(const float4*)p;
        ra1[mi] = *(const float4*)(p + 4);
      } else {
        ra0[mi] = make_float4(0.f, 0.f, 0.f, 0.f);
        ra1[mi] = make_float4(0.f, 0.f, 0.f, 0.f);
      }
    }
    float4 sc0, sc1, sh0, sh1;
    if (FUSE) {
      sc0 = *(const float4*)(scale + kk); sc1 = *(const float4*)(scale + kk + 4);
      sh0 = *(const float4*)(shift + kk); sh1 = *(const float4*)(shift + kk + 4);
    }
    short8v ah[4], al_[4];
#pragma unroll
    for (int mi = 0; mi < 4; ++mi) {
      float v[8];
      v[0] = ra0[mi].x; v[1] = ra0[mi].y; v[2] = ra0[mi].z; v[3] = ra0[mi].w;
      v[4] = ra1[mi].x; v[5] = ra1[mi].y; v[6] = ra1[mi].z; v[7] = ra1[mi].w;
      if (FUSE) {
        float sc[8] = {sc0.x, sc0.y, sc0.z, sc0.w, sc1.x, sc1.y, sc1.z, sc1.w};
        float sh[8] = {sh0.x, sh0.y, sh0.z, sh0.w, sh1.x, sh1.y, sh1.z, sh1.w};
#pragma unroll
        for (int j = 0; j < 8; ++j) {
          float t = fmaf(v[j], sc[j], sh[j]);
          v[j] = t > 0.f ? t : expm1f(t);     // ELU
        }
      }
#pragma unroll
      for (int j = 0; j < 8; ++j) {
        unsigned int ub = __float_as_uint(v[j]);
        unsigned short h = (unsigned short)(ub >> 16);       // trunc hi
        float rem = v[j] - __uint_as_float((unsigned int)h << 16);
        ah[mi][j] = (short)h;
        al_[mi][j] = (short)f2bf(rem);
      }
    }
#pragma unroll
    for (int mi = 0; mi < 4; ++mi)
#pragma unroll
      for (int ni = 0; ni < 4; ++ni) {
        acc[mi][ni] = __builtin_amdgcn_mfma_f32_16x16x32_bf16(ah[mi], bh[ni], acc[mi][ni], 0, 0, 0);
        acc[mi][ni] = __builtin_amdgcn_mfma_f32_16x16x32_bf16(ah[mi], bl[ni], acc[mi][ni], 0, 0, 0);
        acc[mi][ni] = __builtin_amdgcn_mfma_f32_16x16x32_bf16(al_[mi], bh[ni], acc[mi][ni], 0, 0, 0);
      }
  }
  const int cc = lane & 15;
#pragma unroll
  for (int mi = 0; mi < 4; ++mi) {
    int rowb = m0 + mi * 16 + ((lane >> 4) << 2);
#pragma unroll
    for (int r = 0; r < 4; ++r) {
      int row = rowb + r;
      if (row < M) {
#pragma unroll
        for (int ni = 0; ni < 4; ++ni)
          C[(size_t)row * Nw + n0 + ni * 16 + cc] = f2bf(acc[mi][ni][r]);
      }
    }
  }
}

// ---------------- attention logits from bf16 h ----------------
template<int H>
__global__ void al_kernel(const unsigned short* __restrict__ h, const float* __restrict__ a_s,
                          const float* __restrict__ a_d, float* __restrict__ al_s,
                          float* __restrict__ al_d, int N)
{
  int n = blockIdx.x;
  int tid = threadIdx.x;
  int hh = tid >> 6, lane = tid & 63;
  float hv = bf2f(h[(size_t)n * (H * 64) + tid]);
  float ps = hv * a_s[tid];
  float pd = hv * a_d[tid];
  ps = warp_sum64(ps);
  pd = warp_sum64(pd);
  if (lane == 0) { al_s[n * H + hh] = ps; al_d[n * H + hh] = pd; }
}

// ---------------- per-position exp(leaky_relu), CSR order, no atomics ----------------
template<int H>
__global__ void edge_kernel(const int* __restrict__ csrSrc, const int* __restrict__ csrDst,
                            int Etot, const float* __restrict__ al_s,
                            const float* __restrict__ al_d, float* __restrict__ eeCsr)
{
  int t = blockIdx.x * 256 + threadIdx.x;
  if (t >= Etot * H) return;
  int pos = t / H, hh = t - pos * H;
  int s = csrSrc[pos], d = csrDst[pos];
  float x = al_s[s * H + hh] + al_d[d * H + hh];
  x = x > 0.f ? x : 0.2f * x;           // leaky_relu(0.2)
  eeCsr[t] = expf(x);                    // softmax shift-invariant: skip segment max
}

// ---------------- CSR build ----------------
__global__ void count_kernel(const int* __restrict__ dst, int E, int Etot, int* __restrict__ counts)
{
  int e = blockIdx.x * 256 + threadIdx.x;
  if (e >= Etot) return;
  int d = (e < E) ? dst[e] : (e - E);
  atomicAdd(&counts[d], 1);
}

__global__ void block_sum_kernel(const int* __restrict__ counts, int N, int* __restrict__ bsums)
{
  __shared__ int sd[256];
  int i = blockIdx.x * 256 + threadIdx.x;
  sd[threadIdx.x] = (i < N) ? counts[i] : 0;
  __syncthreads();
  for (int off = 128; off; off >>= 1) {
    if (threadIdx.x < off) sd[threadIdx.x] += sd[threadIdx.x + off];
    __syncthreads();
  }
  if (threadIdx.x == 0) bsums[blockIdx.x] = sd[0];
}

// one-block parallel exclusive scan over bsums (nb <= 256)
__global__ void scan_bsums_kernel(int* bsums, int nb)
{
  __shared__ int sd[256];
  int t = threadIdx.x;
  int v = (t < nb) ? bsums[t] : 0;
  sd[t] = v;
  __syncthreads();
  for (int off = 1; off < 256; off <<= 1) {
    int x = (t >= off) ? sd[t - off] : 0;
    __syncthreads();
    sd[t] += x;
    __syncthreads();
  }
  if (t < nb) bsums[t] = sd[t] - v;  // exclusive
}

__global__ void scan_write_kernel(const int* __restrict__ counts, int N,
                                  const int* __restrict__ bsums, int* __restrict__ rowStart, int Etot)
{
  __shared__ int sd[256];
  int i = blockIdx.x * 256 + threadIdx.x;
  int v = (i < N) ? counts[i] : 0;
  sd[threadIdx.x] = v;
  __syncthreads();
  for (int off = 1; off < 256; off <<= 1) {
    int x = (threadIdx.x >= off) ? sd[threadIdx.x - off] : 0;
    __syncthreads();
    sd[threadIdx.x] += x;
    __syncthreads();
  }
  if (i < N) rowStart[i] = bsums[blockIdx.x] + sd[threadIdx.x] - v;  // exclusive
  if (i == N - 1) rowStart[N] = Etot;
}

__global__ void fill_kernel(const int* __restrict__ src, const int* __restrict__ dst,
                            int E, int Etot, const int* __restrict__ rowStart,
                            int* __restrict__ cursor, int* __restrict__ csrSrc,
                            int* __restrict__ csrDst)
{
  int e = blockIdx.x * 256 + threadIdx.x;
  if (e >= Etot) return;
  int s, d;
  if (e < E) { s = src[e]; d = dst[e]; } else { s = d = e - E; }
  int pos = rowStart[d] + atomicAdd(&cursor[d], 1);
  csrSrc[pos] = s;
  csrDst[pos] = d;
}

// ---------------- aggregation: wave per node, bf16 gather, inline denom ----------------
template<int HC_>
__global__ __launch_bounds__(256) void aggregate_kernel(
    const unsigned short* __restrict__ h16, const float* __restrict__ eeCsr,
    const int* __restrict__ csrSrc, const int* __restrict__ rowStart,
    float* __restrict__ outp, int N, const float* __restrict__ bias, int doElu)
{
  constexpr int H_ = HC_ / 64;       // heads (4 or 1)
  constexpr int FPL = HC_ / 64;      // features per lane (4 or 1)
  int wid = (int)(blockIdx.x * (blockDim.x >> 6) + (threadIdx.x >> 6));
  if (wid >= N) return;
  const int lane = threadIdx.x & 63;
  const int head = (H_ == 4) ? (lane >> 4) : 0;
  const int start = rowStart[wid], end = rowStart[wid + 1];

  float acc[FPL] = {};
  float wsum = 0.f;

  for (int base = start; base < end; base += 64) {
    int cnt = end - base; if (cnt > 64) cnt = 64;
    int s_l = (lane < cnt) ? csrSrc[base + lane] : 0;
    int i = 0;
    for (; i + 2 <= cnt; i += 2) {
      int s0 = __shfl(s_l, i);
      int s1 = __shfl(s_l, i + 1);
      float w0 = eeCsr[(size_t)(base + i) * H_ + head];
      float w1 = eeCsr[(size_t)(base + i + 1) * H_ + head];
      if (FPL == 4) {
        ushort4 r0 = ((const ushort4*)(h16 + (size_t)s0 * HC_))[lane];
        ushort4 r1 = ((const ushort4*)(h16 + (size_t)s1 * HC_))[lane];
        wsum += w0 + w1;
        acc[0] = fmaf(w0, bf2f(r0.x), acc[0]);
        acc[1] = fmaf(w0, bf2f(r0.y), acc[1]);
        acc[2] = fmaf(w0, bf2f(r0.z), acc[2]);
        acc[3] = fmaf(w0, bf2f(r0.w), acc[3]);
        acc[0] = fmaf(w1, bf2f(r1.x), acc[0]);
        acc[1] = fmaf(w1, bf2f(r1.y), acc[1]);
        acc[2] = fmaf(w1, bf2f(r1.z), acc[2]);
        acc[3] = fmaf(w1, bf2f(r1.w), acc[3]);
      } else {
        unsigned short r0 = h16[(size_t)s0 * HC_ + lane];
        unsigned short r1 = h16[(size_t)s1 * HC_ + lane];
        wsum += w0 + w1;
        acc[0] = fmaf(w0, bf2f(r0), acc[0]);
        acc[0] = fmaf(w1, bf2f(r1), acc[0]);
      }
    }
    if (i < cnt) {
      int s0 = __shfl(s_l, i);
      float w0 = eeCsr[(size_t)(base + i) * H_ + head];
      wsum += w0;
      if (FPL == 4) {
        ushort4 r0 = ((const ushort4*)(h16 + (size_t)s0 * HC_))[lane];
        acc[0] = fmaf(w0, bf2f(r0.x), acc[0]);
        acc[1] = fmaf(w0, bf2f(r0.y), acc[1]);
        acc[2] = fmaf(w0, bf2f(r0.z), acc[2]);
        acc[3] = fmaf(w0, bf2f(r0.w), acc[3]);
      } else {
        unsigned short r0 = h16[(size_t)s0 * HC_ + lane];
        acc[0] = fmaf(w0, bf2f(r0), acc[0]);
      }
    }
  }

  float inv = 1.0f / wsum;
  if (FPL == 4) {
    float4 o;
    o.x = acc[0] * inv; o.y = acc[1] * inv; o.z = acc[2] * inv; o.w = acc[3] * inv;
    if (bias) {
      const float4 b = ((const float4*)bias)[lane];
      o.x += b.x; o.y += b.y; o.z += b.z; o.w += b.w;
    }
    if (doElu) {
      o.x = o.x > 0.f ? o.x : expm1f(o.x);
      o.y = o.y > 0.f ? o.y : expm1f(o.y);
      o.z = o.z > 0.f ? o.z : expm1f(o.z);
      o.w = o.w > 0.f ? o.w : expm1f(o.w);
    }
    ((float4*)(outp + (size_t)wid * HC_))[lane] = o;
  } else {
    float o = acc[0] * inv;
    if (bias) o += bias[lane];
    if (doElu) o = o > 0.f ? o : expm1f(o);
    outp[(size_t)wid * HC_ + lane] = o;
  }
}

// ---------------- batch norm stats: wave-per-row-group, float4, LDS reduce ----------------
__global__ __launch_bounds__(256) void bn_stats_kernel(const float* __restrict__ x, int N,
                                float* __restrict__ sums, float* __restrict__ sumsq)
{
  const int wid = threadIdx.x >> 6, lane = threadIdx.x & 63;
  const int gw = blockIdx.x * 4 + wid;         // global wave id
  const int tw = gridDim.x * 4;                // total waves
  float4 s = make_float4(0.f, 0.f, 0.f, 0.f);
  float4 q = make_float4(0.f, 0.f, 0.f, 0.f);
#pragma unroll 4
  for (int r = gw; r < N; r += tw) {
    float4 v = ((const float4*)(x + (size_t)r * 256))[lane];
    s.x += v.x; s.y += v.y; s.z += v.z; s.w += v.w;
    q.x = fmaf(v.x, v.x, q.x); q.y = fmaf(v.y, v.y, q.y);
    q.z = fmaf(v.z, v.z, q.z); q.w = fmaf(v.w, v.w, q.w);
  }
  __shared__ float ls[4][512];
  *(float4*)&ls[wid][lane * 4] = s;
  *(float4*)&ls[wid][256 + lane * 4] = q;
  __syncthreads();
  const int t = threadIdx.x;
  float a = ls[0][t] + ls[1][t] + ls[2][t] + ls[3][t];
  float b = ls[0][t + 256] + ls[1][t + 256] + ls[2][t + 256] + ls[3][t + 256];
  atomicAdd(&sums[t], a);
  atomicAdd(&sumsq[t], b);
}

__global__ void bn_final_kernel(const float* __restrict__ sums, const float* __restrict__ sumsq,
                                const float* __restrict__ g, const float* __restrict__ be,
                                int N, float* __restrict__ scale, float* __restrict__ shift)
{
  int f = threadIdx.x;
  float mu = sums[f] / N;
  float var = sumsq[f] / N - mu * mu;
  float rs = rsqrtf(var + 1e-5f);
  float sc = g[f] * rs;
  scale[f] = sc;
  shift[f] = be[f] - mu * sc;
}

// ---------------- MLP head ----------------
__global__ __launch_bounds__(256) void mlp_kernel(const float* __restrict__ h,
                           const float* __restrict__ fw1,
                           const float* __restrict__ fb1, const float* __restrict__ fw2,
                           const float* __restrict__ fb2, float* __restrict__ out, int N)
{
  const int lane = threadIdx.x & 63;
  const int j = lane & 31;
  const int col = lane >> 5;
  float w1c[64];
#pragma unroll
  for (int k = 0; k < 64; ++k) w1c[k] = fw1[k * 32 + j];
  const float b1v = fb1[j];
  const float w2v = fw2[j * 2 + col];
  const float b2v = fb2[col];

  const int nwaves = (int)(gridDim.x * (blockDim.x >> 6));
  int wid = (int)(blockIdx.x * (blockDim.x >> 6) + (threadIdx.x >> 6));
  for (int n = wid; n < N; n += nwaves) {
    float hv = h[(size_t)n * 64 + lane];
    float acc = 0.f;
#pragma unroll
    for (int k = 0; k < 64; ++k) {
      float s = __shfl(hv, k);
      acc = fmaf(s, w1c[k], acc);
    }
    float hid = fmaxf(acc + b1v, 0.f);
    float p = hid * w2v;
#pragma unroll
    for (int off = 16; off; off >>= 1) p += __shfl_xor(p, off);
    if (j == 0) out[(size_t)n * 2 + col] = p + b2v;
  }
}

// ---------------- host ----------------
extern "C" void kernel_launch(void* const* d_in, const int* in_sizes, int n_in,
                              void* d_out, int out_size, void* d_ws, size_t ws_size,
                              hipStream_t stream)
{
  const float* x   = (const float*)d_in[0];
  const int*   ei  = (const int*)d_in[1];
  const float* W1  = (const float*)d_in[2];
  const float* a1s = (const float*)d_in[3];
  const float* a1d = (const float*)d_in[4];
  const float* W2  = (const float*)d_in[6];
  const float* a2s = (const float*)d_in[7];
  const float* a2d = (const float*)d_in[8];
  const float* W3  = (const float*)d_in[10];
  const float* a3s = (const float*)d_in[11];
  const float* a3d = (const float*)d_in[12];
  const float* b3  = (const float*)d_in[13];
  const float* g1  = (const float*)d_in[14];
  const float* be1 = (const float*)d_in[15];
  const float* g2  = (const float*)d_in[16];
  const float* be2 = (const float*)d_in[17];
  const float* fw1 = (const float*)d_in[18];
  const float* fb1 = (const float*)d_in[19];
  const float* fw2 = (const float*)d_in[20];
  const float* fb2 = (const float*)d_in[21];
  float* out = (float*)d_out;

  const int F = 128;
  const int N = in_sizes[0] / F;
  const int E = in_sizes[1] / 2;
  const int Etot = E + N;
  const int* srcIdx = ei;
  const int* dstIdx = ei + E;

  // workspace layout (256B aligned slices)
  char* w = (char*)d_ws;
  auto alloc = [&](size_t bytes) -> void* {
    void* p = (void*)w;
    w += (bytes + 255) & ~(size_t)255;
    return p;
  };
  unsigned short* h16 = (unsigned short*)alloc((size_t)N * 256 * 2);
  float* act     = (float*)alloc((size_t)N * 256 * 4);
  float* eeCsr   = (float*)alloc((size_t)Etot * 4 * 4);
  float* als     = (float*)alloc((size_t)N * 4 * 4);
  float* ald     = (float*)alloc((size_t)N * 4 * 4);
  int*   counts  = (int*)alloc((size_t)N * 4);
  int*   cursor  = (int*)alloc((size_t)N * 4);
  int*   rowStart= (int*)alloc((size_t)(N + 1) * 4);
  int*   csrSrc  = (int*)alloc((size_t)Etot * 4);
  int*   csrDst  = (int*)alloc((size_t)Etot * 4);
  int*   bsums   = (int*)alloc((size_t)((N + 255) / 256) * 4);
  float* sums    = (float*)alloc(256 * 4);
  float* sumsq   = (float*)alloc(256 * 4);
  float* scale1  = (float*)alloc(256 * 4);
  float* shift1  = (float*)alloc(256 * 4);
  float* scale2  = (float*)alloc(256 * 4);
  float* shift2  = (float*)alloc(256 * 4);
  unsigned short* w1h = (unsigned short*)alloc((size_t)128 * 256 * 2);
  unsigned short* w1l = (unsigned short*)alloc((size_t)128 * 256 * 2);
  unsigned short* w2h = (unsigned short*)alloc((size_t)256 * 256 * 2);
  unsigned short* w2l = (unsigned short*)alloc((size_t)256 * 256 * 2);
  unsigned short* w3h = (unsigned short*)alloc((size_t)256 * 64 * 2);
  unsigned short* w3l = (unsigned short*)alloc((size_t)256 * 64 * 2);

  const int nb = (N + 255) / 256;
  const int ebk = (Etot + 255) / 256;
  const int aggBlocks = (N + 3) / 4;

  // ---- weight prep (frag-ordered bf16 hi/lo) ----
  wprep_kernel<<<(128 * 256 + 255) / 256, 256, 0, stream>>>(W1, w1h, w1l, 128, 256);
  wprep_kernel<<<(256 * 256 + 255) / 256, 256, 0, stream>>>(W2, w2h, w2l, 256, 256);
  wprep_kernel<<<(256 * 64 + 255) / 256, 256, 0, stream>>>(W3, w3h, w3l, 256, 64);

  // ---- CSR build (reused by all 3 layers) ----
  hipMemsetAsync(counts, 0, (size_t)N * 4, stream);
  hipMemsetAsync(cursor, 0, (size_t)N * 4, stream);
  count_kernel<<<ebk, 256, 0, stream>>>(dstIdx, E, Etot, counts);
  block_sum_kernel<<<nb, 256, 0, stream>>>(counts, N, bsums);
  scan_bsums_kernel<<<1, 256, 0, stream>>>(bsums, nb);
  scan_write_kernel<<<nb, 256, 0, stream>>>(counts, N, bsums, rowStart, Etot);
  fill_kernel<<<ebk, 256, 0, stream>>>(srcIdx, dstIdx, E, Etot, rowStart, cursor, csrSrc, csrDst);

  dim3 g12((N + 127) / 128, 2);   // layers 1,2: BM=128, BN=128, N=256
  dim3 g3((N + 255) / 256, 1);    // layer 3: BM=256, BN=64

  // ---- GAT layer 1: x[N,128] -> act[N,256] (bias cancels in BN) ----
  gemm_mfma<2, 2, false><<<g12, 256, 0, stream>>>(x, w1h, w1l, nullptr, nullptr, h16, N, 256, 128);
  al_kernel<4><<<N, 256, 0, stream>>>(h16, a1s, a1d, als, ald, N);
  edge_kernel<4><<<(Etot * 4 + 255) / 256, 256, 0, stream>>>(csrSrc, csrDst, Etot, als, ald, eeCsr);
  aggregate_kernel<256><<<aggBlocks, 256, 0, stream>>>(h16, eeCsr, csrSrc, rowStart, act, N, nullptr, 0);
  // BN1 stats -> scale1/shift1 (apply+ELU fused into next GEMM's A-load)
  hipMemsetAsync(sums, 0, 256 * 4, stream);
  hipMemsetAsync(sumsq, 0, 256 * 4, stream);
  bn_stats_kernel<<<512, 256, 0, stream>>>(act, N, sums, sumsq);
  bn_final_kernel<<<1, 256, 0, stream>>>(sums, sumsq, g1, be1, N, scale1, shift1);

  // ---- GAT layer 2: elu(bn(act)) @ W2 -> h16 ----
  gemm_mfma<2, 2, true><<<g12, 256, 0, stream>>>(act, w2h, w2l, scale1, shift1, h16, N, 256, 256);
  al_kernel<4><<<N, 256, 0, stream>>>(h16, a2s, a2d, als, ald, N);
  edge_kernel<4><<<(Etot * 4 + 255) / 256, 256, 0, stream>>>(csrSrc, csrDst, Etot, als, ald, eeCsr);
  aggregate_kernel<256><<<aggBlocks, 256, 0, stream>>>(h16, eeCsr, csrSrc, rowStart, act, N, nullptr, 0);
  // BN2 stats -> scale2/shift2
  hipMemsetAsync(sums, 0, 256 * 4, stream);
  hipMemsetAsync(sumsq, 0, 256 * 4, stream);
  bn_stats_kernel<<<512, 256, 0, stream>>>(act, N, sums, sumsq);
  bn_final_kernel<<<1, 256, 0, stream>>>(sums, sumsq, g2, be2, N, scale2, shift2);

  // ---- GAT layer 3 (1 head, C=64): elu(bn(act)) @ W3 -> h16[N,64]; agg +b3, ELU ----
  gemm_mfma<4, 1, true><<<g3, 256, 0, stream>>>(act, w3h, w3l, scale2, shift2, h16, N, 64, 256);
  al_kernel<1><<<N, 64, 0, stream>>>(h16, a3s, a3d, als, ald, N);
  edge_kernel<1><<<(Etot + 255) / 256, 256, 0, stream>>>(csrSrc, csrDst, Etot, als, ald, eeCsr);
  aggregate_kernel<64><<<aggBlocks, 256, 0, stream>>>(h16, eeCsr, csrSrc, rowStart, act, N, b3, 1);

  // ---- MLP head ----
  mlp_kernel<<<1024, 256, 0, stream>>>(act, fw1, fb1, fw2, fb2, out, N);
}

// Round 6
// 485.617 us; speedup vs baseline: 2.4548x; 1.0314x over previous
//
#include <hip/hip_runtime.h>
#include <math.h>
#include <stdint.h>

typedef __attribute__((ext_vector_type(8))) short short8v;
typedef __attribute__((ext_vector_type(4))) float float4v;

// ---------------- utility ----------------
__device__ __forceinline__ float warp_sum64(float v) {
#pragma unroll
  for (int off = 32; off; off >>= 1) v += __shfl_xor(v, off);
  return v;
}

__device__ __forceinline__ float bf2f(unsigned short u) {
  return __uint_as_float((unsigned int)u << 16);
}
__device__ __forceinline__ unsigned short f2bf(float f) {   // RNE
  unsigned int u = __float_as_uint(f);
  unsigned int r = (u + 0x7FFFu + ((u >> 16) & 1u)) >> 16;
  return (unsigned short)r;
}

// ---------------- weight prep: fp32 W[K][Nw] -> hi/lo bf16 in MFMA-frag order ----
__global__ void wprep_kernel(const float* __restrict__ W, unsigned short* __restrict__ Wh,
                             unsigned short* __restrict__ Wl, int K, int Nw)
{
  int t = blockIdx.x * 256 + threadIdx.x;
  if (t >= K * Nw) return;
  int i = t & 7;
  int lane = (t >> 3) & 63;
  int frag = t >> 9;
  int ktiles = K >> 5;
  int n_tile = frag / ktiles, k_tile = frag - n_tile * ktiles;
  int k = k_tile * 32 + ((lane >> 4) << 3) + i;
  int n = (n_tile << 4) + (lane & 15);
  float v = W[(size_t)k * Nw + n];
  unsigned short hi = (unsigned short)(__float_as_uint(v) >> 16);   // trunc
  float rem = v - bf2f(hi);
  Wh[t] = hi;
  Wl[t] = f2bf(rem);
}

// ---------------- A-side split passes (conversion done ONCE, outside GEMM) ----
// plain split: in fp32 -> hi/lo bf16, elementwise
__global__ __launch_bounds__(256) void split_kernel(const float* __restrict__ in,
    unsigned short* __restrict__ hi, unsigned short* __restrict__ lo, size_t n4)
{
  size_t i0 = (size_t)blockIdx.x * 256 + threadIdx.x;
  size_t stride = (size_t)gridDim.x * 256;
  for (size_t idx = i0; idx < n4; idx += stride) {
    float4 v = ((const float4*)in)[idx];
    float vv[4] = {v.x, v.y, v.z, v.w};
    ushort4 h, l;
    unsigned short* hp = &h.x; unsigned short* lp = &l.x;
#pragma unroll
    for (int j = 0; j < 4; ++j) {
      unsigned short hh = (unsigned short)(__float_as_uint(vv[j]) >> 16);
      hp[j] = hh;
      lp[j] = f2bf(vv[j] - bf2f(hh));
    }
    ((ushort4*)hi)[idx] = h;
    ((ushort4*)lo)[idx] = l;
  }
}

// BN(scale,shift) + ELU + split: act [N][256] fp32 -> hi/lo bf16
__global__ __launch_bounds__(256) void bnsplit_kernel(const float* __restrict__ act,
    const float* __restrict__ scale, const float* __restrict__ shift,
    unsigned short* __restrict__ hi, unsigned short* __restrict__ lo, size_t n4)
{
  size_t i0 = (size_t)blockIdx.x * 256 + threadIdx.x;
  size_t stride = (size_t)gridDim.x * 256;
  for (size_t idx = i0; idx < n4; idx += stride) {
    float4 v = ((const float4*)act)[idx];
    int f = (int)((idx * 4) & 255);
    float4 sc = *(const float4*)(scale + f);
    float4 sh = *(const float4*)(shift + f);
    float vv[4];
    vv[0] = fmaf(v.x, sc.x, sh.x);
    vv[1] = fmaf(v.y, sc.y, sh.y);
    vv[2] = fmaf(v.z, sc.z, sh.z);
    vv[3] = fmaf(v.w, sc.w, sh.w);
    ushort4 h, l;
    unsigned short* hp = &h.x; unsigned short* lp = &l.x;
#pragma unroll
    for (int j = 0; j < 4; ++j) {
      float t = vv[j];
      t = t > 0.f ? t : expm1f(t);                 // ELU
      unsigned short hh = (unsigned short)(__float_as_uint(t) >> 16);
      hp[j] = hh;
      lp[j] = f2bf(t - bf2f(hh));
    }
    ((ushort4*)hi)[idx] = h;
    ((ushort4*)lo)[idx] = l;
  }
}

// ---------------- MFMA GEMM: C[M,Nw](bf16) = (Ah+Al)[M,K] @ (Bh+Bl) ----------------
// A row-major pre-split bf16; B pre-split in frag order. Pure load+MFMA.
template<int WM, int WN>
__global__ __launch_bounds__(256) void gemm_mfma(
    const unsigned short* __restrict__ Ah, const unsigned short* __restrict__ Al,
    const unsigned short* __restrict__ Bh, const unsigned short* __restrict__ Bl,
    unsigned short* __restrict__ C, int M, int Nw, int K)
{
  constexpr int BM = WM * 64, BN = WN * 64;
  const int wid = threadIdx.x >> 6, lane = threadIdx.x & 63;
  const int wm = wid / WN, wn = wid % WN;
  const int m0 = blockIdx.x * BM + wm * 64;
  const int n0 = blockIdx.y * BN + wn * 64;
  const int ar = lane & 15;
  const int kb = (lane >> 4) << 3;
  const int ktiles = K >> 5;
  const int ntile0 = n0 >> 4;

  float4v acc[4][4];
#pragma unroll
  for (int mi = 0; mi < 4; ++mi)
#pragma unroll
    for (int ni = 0; ni < 4; ++ni)
      acc[mi][ni] = (float4v){0.f, 0.f, 0.f, 0.f};

  for (int kt = 0; kt < ktiles; ++kt) {
    const int kk = kt * 32 + kb;
    short8v bh[4], bl[4];
#pragma unroll
    for (int ni = 0; ni < 4; ++ni) {
      size_t off = (((size_t)(ntile0 + ni) * ktiles + kt) * 64 + lane) * 8;
      bh[ni] = *(const short8v*)(Bh + off);
      bl[ni] = *(const short8v*)(Bl + off);
    }
    short8v ah[4], al_[4];
#pragma unroll
    for (int mi = 0; mi < 4; ++mi) {
      int row = m0 + mi * 16 + ar;
      if (row < M) {
        size_t off = (size_t)row * K + kk;
        ah[mi] = *(const short8v*)(Ah + off);
        al_[mi] = *(const short8v*)(Al + off);
      } else {
        ah[mi] = (short8v){0, 0, 0, 0, 0, 0, 0, 0};
        al_[mi] = (short8v){0, 0, 0, 0, 0, 0, 0, 0};
      }
    }
#pragma unroll
    for (int mi = 0; mi < 4; ++mi)
#pragma unroll
      for (int ni = 0; ni < 4; ++ni) {
        acc[mi][ni] = __builtin_amdgcn_mfma_f32_16x16x32_bf16(ah[mi], bh[ni], acc[mi][ni], 0, 0, 0);
        acc[mi][ni] = __builtin_amdgcn_mfma_f32_16x16x32_bf16(ah[mi], bl[ni], acc[mi][ni], 0, 0, 0);
        acc[mi][ni] = __builtin_amdgcn_mfma_f32_16x16x32_bf16(al_[mi], bh[ni], acc[mi][ni], 0, 0, 0);
      }
  }
  const int cc = lane & 15;
#pragma unroll
  for (int mi = 0; mi < 4; ++mi) {
    int rowb = m0 + mi * 16 + ((lane >> 4) << 2);
#pragma unroll
    for (int r = 0; r < 4; ++r) {
      int row = rowb + r;
      if (row < M) {
#pragma unroll
        for (int ni = 0; ni < 4; ++ni)
          C[(size_t)row * Nw + n0 + ni * 16 + cc] = f2bf(acc[mi][ni][r]);
      }
    }
  }
}

// ---------------- attention logits from bf16 h ----------------
template<int H>
__global__ void al_kernel(const unsigned short* __restrict__ h, const float* __restrict__ a_s,
                          const float* __restrict__ a_d, float* __restrict__ al_s,
                          float* __restrict__ al_d, int N)
{
  int n = blockIdx.x;
  int tid = threadIdx.x;
  int hh = tid >> 6, lane = tid & 63;
  float hv = bf2f(h[(size_t)n * (H * 64) + tid]);
  float ps = hv * a_s[tid];
  float pd = hv * a_d[tid];
  ps = warp_sum64(ps);
  pd = warp_sum64(pd);
  if (lane == 0) { al_s[n * H + hh] = ps; al_d[n * H + hh] = pd; }
}

// ---------------- per-position exp(leaky_relu), CSR order, no atomics ----------------
template<int H>
__global__ void edge_kernel(const int* __restrict__ csrSrc, const int* __restrict__ csrDst,
                            int Etot, const float* __restrict__ al_s,
                            const float* __restrict__ al_d, float* __restrict__ eeCsr)
{
  int t = blockIdx.x * 256 + threadIdx.x;
  if (t >= Etot * H) return;
  int pos = t / H, hh = t - pos * H;
  int s = csrSrc[pos], d = csrDst[pos];
  float x = al_s[s * H + hh] + al_d[d * H + hh];
  x = x > 0.f ? x : 0.2f * x;           // leaky_relu(0.2)
  eeCsr[t] = expf(x);                    // softmax shift-invariant: skip segment max
}

// ---------------- CSR build ----------------
__global__ void count_kernel(const int* __restrict__ dst, int E, int Etot, int* __restrict__ counts)
{
  int e = blockIdx.x * 256 + threadIdx.x;
  if (e >= Etot) return;
  int d = (e < E) ? dst[e] : (e - E);
  atomicAdd(&counts[d], 1);
}

__global__ void block_sum_kernel(const int* __restrict__ counts, int N, int* __restrict__ bsums)
{
  __shared__ int sd[256];
  int i = blockIdx.x * 256 + threadIdx.x;
  sd[threadIdx.x] = (i < N) ? counts[i] : 0;
  __syncthreads();
  for (int off = 128; off; off >>= 1) {
    if (threadIdx.x < off) sd[threadIdx.x] += sd[threadIdx.x + off];
    __syncthreads();
  }
  if (threadIdx.x == 0) bsums[blockIdx.x] = sd[0];
}

// one-block parallel exclusive scan over bsums (nb <= 256)
__global__ void scan_bsums_kernel(int* bsums, int nb)
{
  __shared__ int sd[256];
  int t = threadIdx.x;
  int v = (t < nb) ? bsums[t] : 0;
  sd[t] = v;
  __syncthreads();
  for (int off = 1; off < 256; off <<= 1) {
    int x = (t >= off) ? sd[t - off] : 0;
    __syncthreads();
    sd[t] += x;
    __syncthreads();
  }
  if (t < nb) bsums[t] = sd[t] - v;  // exclusive
}

__global__ void scan_write_kernel(const int* __restrict__ counts, int N,
                                  const int* __restrict__ bsums, int* __restrict__ rowStart, int Etot)
{
  __shared__ int sd[256];
  int i = blockIdx.x * 256 + threadIdx.x;
  int v = (i < N) ? counts[i] : 0;
  sd[threadIdx.x] = v;
  __syncthreads();
  for (int off = 1; off < 256; off <<= 1) {
    int x = (threadIdx.x >= off) ? sd[threadIdx.x - off] : 0;
    __syncthreads();
    sd[threadIdx.x] += x;
    __syncthreads();
  }
  if (i < N) rowStart[i] = bsums[blockIdx.x] + sd[threadIdx.x] - v;  // exclusive
  if (i == N - 1) rowStart[N] = Etot;
}

__global__ void fill_kernel(const int* __restrict__ src, const int* __restrict__ dst,
                            int E, int Etot, const int* __restrict__ rowStart,
                            int* __restrict__ cursor, int* __restrict__ csrSrc,
                            int* __restrict__ csrDst)
{
  int e = blockIdx.x * 256 + threadIdx.x;
  if (e >= Etot) return;
  int s, d;
  if (e < E) { s = src[e]; d = dst[e]; } else { s = d = e - E; }
  int pos = rowStart[d] + atomicAdd(&cursor[d], 1);
  csrSrc[pos] = s;
  csrDst[pos] = d;
}

// ---------------- aggregation: wave per node, bf16 gather, inline denom, 4x ILP ----
template<int HC_>
__global__ __launch_bounds__(256) void aggregate_kernel(
    const unsigned short* __restrict__ h16, const float* __restrict__ eeCsr,
    const int* __restrict__ csrSrc, const int* __restrict__ rowStart,
    float* __restrict__ outp, int N, const float* __restrict__ bias, int doElu)
{
  constexpr int H_ = HC_ / 64;       // heads (4 or 1)
  constexpr int FPL = HC_ / 64;      // features per lane (4 or 1)
  int wid = (int)(blockIdx.x * (blockDim.x >> 6) + (threadIdx.x >> 6));
  if (wid >= N) return;
  const int lane = threadIdx.x & 63;
  const int head = (H_ == 4) ? (lane >> 4) : 0;
  const int start = rowStart[wid], end = rowStart[wid + 1];

  float acc[FPL] = {};
  float wsum = 0.f;

  for (int base = start; base < end; base += 64) {
    int cnt = end - base; if (cnt > 64) cnt = 64;
    int s_l = (lane < cnt) ? csrSrc[base + lane] : 0;
    int i = 0;
    for (; i + 4 <= cnt; i += 4) {
      int s0 = __shfl(s_l, i);
      int s1 = __shfl(s_l, i + 1);
      int s2 = __shfl(s_l, i + 2);
      int s3 = __shfl(s_l, i + 3);
      float w0 = eeCsr[(size_t)(base + i) * H_ + head];
      float w1 = eeCsr[(size_t)(base + i + 1) * H_ + head];
      float w2 = eeCsr[(size_t)(base + i + 2) * H_ + head];
      float w3 = eeCsr[(size_t)(base + i + 3) * H_ + head];
      if (FPL == 4) {
        ushort4 r0 = ((const ushort4*)(h16 + (size_t)s0 * HC_))[lane];
        ushort4 r1 = ((const ushort4*)(h16 + (size_t)s1 * HC_))[lane];
        ushort4 r2 = ((const ushort4*)(h16 + (size_t)s2 * HC_))[lane];
        ushort4 r3 = ((const ushort4*)(h16 + (size_t)s3 * HC_))[lane];
        wsum += (w0 + w1) + (w2 + w3);
        acc[0] = fmaf(w0, bf2f(r0.x), acc[0]);
        acc[1] = fmaf(w0, bf2f(r0.y), acc[1]);
        acc[2] = fmaf(w0, bf2f(r0.z), acc[2]);
        acc[3] = fmaf(w0, bf2f(r0.w), acc[3]);
        acc[0] = fmaf(w1, bf2f(r1.x), acc[0]);
        acc[1] = fmaf(w1, bf2f(r1.y), acc[1]);
        acc[2] = fmaf(w1, bf2f(r1.z), acc[2]);
        acc[3] = fmaf(w1, bf2f(r1.w), acc[3]);
        acc[0] = fmaf(w2, bf2f(r2.x), acc[0]);
        acc[1] = fmaf(w2, bf2f(r2.y), acc[1]);
        acc[2] = fmaf(w2, bf2f(r2.z), acc[2]);
        acc[3] = fmaf(w2, bf2f(r2.w), acc[3]);
        acc[0] = fmaf(w3, bf2f(r3.x), acc[0]);
        acc[1] = fmaf(w3, bf2f(r3.y), acc[1]);
        acc[2] = fmaf(w3, bf2f(r3.z), acc[2]);
        acc[3] = fmaf(w3, bf2f(r3.w), acc[3]);
      } else {
        unsigned short r0 = h16[(size_t)s0 * HC_ + lane];
        unsigned short r1 = h16[(size_t)s1 * HC_ + lane];
        unsigned short r2 = h16[(size_t)s2 * HC_ + lane];
        unsigned short r3 = h16[(size_t)s3 * HC_ + lane];
        wsum += (w0 + w1) + (w2 + w3);
        acc[0] = fmaf(w0, bf2f(r0), acc[0]);
        acc[0] = fmaf(w1, bf2f(r1), acc[0]);
        acc[0] = fmaf(w2, bf2f(r2), acc[0]);
        acc[0] = fmaf(w3, bf2f(r3), acc[0]);
      }
    }
    for (; i < cnt; ++i) {
      int s0 = __shfl(s_l, i);
      float w0 = eeCsr[(size_t)(base + i) * H_ + head];
      wsum += w0;
      if (FPL == 4) {
        ushort4 r0 = ((const ushort4*)(h16 + (size_t)s0 * HC_))[lane];
        acc[0] = fmaf(w0, bf2f(r0.x), acc[0]);
        acc[1] = fmaf(w0, bf2f(r0.y), acc[1]);
        acc[2] = fmaf(w0, bf2f(r0.z), acc[2]);
        acc[3] = fmaf(w0, bf2f(r0.w), acc[3]);
      } else {
        unsigned short r0 = h16[(size_t)s0 * HC_ + lane];
        acc[0] = fmaf(w0, bf2f(r0), acc[0]);
      }
    }
  }

  float inv = 1.0f / wsum;
  if (FPL == 4) {
    float4 o;
    o.x = acc[0] * inv; o.y = acc[1] * inv; o.z = acc[2] * inv; o.w = acc[3] * inv;
    if (bias) {
      const float4 b = ((const float4*)bias)[lane];
      o.x += b.x; o.y += b.y; o.z += b.z; o.w += b.w;
    }
    if (doElu) {
      o.x = o.x > 0.f ? o.x : expm1f(o.x);
      o.y = o.y > 0.f ? o.y : expm1f(o.y);
      o.z = o.z > 0.f ? o.z : expm1f(o.z);
      o.w = o.w > 0.f ? o.w : expm1f(o.w);
    }
    ((float4*)(outp + (size_t)wid * HC_))[lane] = o;
  } else {
    float o = acc[0] * inv;
    if (bias) o += bias[lane];
    if (doElu) o = o > 0.f ? o : expm1f(o);
    outp[(size_t)wid * HC_ + lane] = o;
  }
}

// ---------------- batch norm stats: wave-per-row-group, float4, LDS reduce ----------------
__global__ __launch_bounds__(256) void bn_stats_kernel(const float* __restrict__ x, int N,
                                float* __restrict__ sums, float* __restrict__ sumsq)
{
  const int wid = threadIdx.x >> 6, lane = threadIdx.x & 63;
  const int gw = blockIdx.x * 4 + wid;         // global wave id
  const int tw = gridDim.x * 4;                // total waves
  float4 s = make_float4(0.f, 0.f, 0.f, 0.f);
  float4 q = make_float4(0.f, 0.f, 0.f, 0.f);
#pragma unroll 4
  for (int r = gw; r < N; r += tw) {
    float4 v = ((const float4*)(x + (size_t)r * 256))[lane];
    s.x += v.x; s.y += v.y; s.z += v.z; s.w += v.w;
    q.x = fmaf(v.x, v.x, q.x); q.y = fmaf(v.y, v.y, q.y);
    q.z = fmaf(v.z, v.z, q.z); q.w = fmaf(v.w, v.w, q.w);
  }
  __shared__ float ls[4][512];
  *(float4*)&ls[wid][lane * 4] = s;
  *(float4*)&ls[wid][256 + lane * 4] = q;
  __syncthreads();
  const int t = threadIdx.x;
  float a = ls[0][t] + ls[1][t] + ls[2][t] + ls[3][t];
  float b = ls[0][t + 256] + ls[1][t + 256] + ls[2][t + 256] + ls[3][t + 256];
  atomicAdd(&sums[t], a);
  atomicAdd(&sumsq[t], b);
}

__global__ void bn_final_kernel(const float* __restrict__ sums, const float* __restrict__ sumsq,
                                const float* __restrict__ g, const float* __restrict__ be,
                                int N, float* __restrict__ scale, float* __restrict__ shift)
{
  int f = threadIdx.x;
  float mu = sums[f] / N;
  float var = sumsq[f] / N - mu * mu;
  float rs = rsqrtf(var + 1e-5f);
  float sc = g[f] * rs;
  scale[f] = sc;
  shift[f] = be[f] - mu * sc;
}

// ---------------- MLP head ----------------
__global__ __launch_bounds__(256) void mlp_kernel(const float* __restrict__ h,
                           const float* __restrict__ fw1,
                           const float* __restrict__ fb1, const float* __restrict__ fw2,
                           const float* __restrict__ fb2, float* __restrict__ out, int N)
{
  const int lane = threadIdx.x & 63;
  const int j = lane & 31;
  const int col = lane >> 5;
  float w1c[64];
#pragma unroll
  for (int k = 0; k < 64; ++k) w1c[k] = fw1[k * 32 + j];
  const float b1v = fb1[j];
  const float w2v = fw2[j * 2 + col];
  const float b2v = fb2[col];

  const int nwaves = (int)(gridDim.x * (blockDim.x >> 6));
  int wid = (int)(blockIdx.x * (blockDim.x >> 6) + (threadIdx.x >> 6));
  for (int n = wid; n < N; n += nwaves) {
    float hv = h[(size_t)n * 64 + lane];
    float acc = 0.f;
#pragma unroll
    for (int k = 0; k < 64; ++k) {
      float s = __shfl(hv, k);
      acc = fmaf(s, w1c[k], acc);
    }
    float hid = fmaxf(acc + b1v, 0.f);
    float p = hid * w2v;
#pragma unroll
    for (int off = 16; off; off >>= 1) p += __shfl_xor(p, off);
    if (j == 0) out[(size_t)n * 2 + col] = p + b2v;
  }
}

// ---------------- host ----------------
extern "C" void kernel_launch(void* const* d_in, const int* in_sizes, int n_in,
                              void* d_out, int out_size, void* d_ws, size_t ws_size,
                              hipStream_t stream)
{
  const float* x   = (const float*)d_in[0];
  const int*   ei  = (const int*)d_in[1];
  const float* W1  = (const float*)d_in[2];
  const float* a1s = (const float*)d_in[3];
  const float* a1d = (const float*)d_in[4];
  const float* W2  = (const float*)d_in[6];
  const float* a2s = (const float*)d_in[7];
  const float* a2d = (const float*)d_in[8];
  const float* W3  = (const float*)d_in[10];
  const float* a3s = (const float*)d_in[11];
  const float* a3d = (const float*)d_in[12];
  const float* b3  = (const float*)d_in[13];
  const float* g1  = (const float*)d_in[14];
  const float* be1 = (const float*)d_in[15];
  const float* g2  = (const float*)d_in[16];
  const float* be2 = (const float*)d_in[17];
  const float* fw1 = (const float*)d_in[18];
  const float* fb1 = (const float*)d_in[19];
  const float* fw2 = (const float*)d_in[20];
  const float* fb2 = (const float*)d_in[21];
  float* out = (float*)d_out;

  const int F = 128;
  const int N = in_sizes[0] / F;
  const int E = in_sizes[1] / 2;
  const int Etot = E + N;
  const int* srcIdx = ei;
  const int* dstIdx = ei + E;

  // workspace layout (256B aligned slices)
  char* w = (char*)d_ws;
  auto alloc = [&](size_t bytes) -> void* {
    void* p = (void*)w;
    w += (bytes + 255) & ~(size_t)255;
    return p;
  };
  unsigned short* h16 = (unsigned short*)alloc((size_t)N * 256 * 2);
  float* act     = (float*)alloc((size_t)N * 256 * 4);
  unsigned short* aHi = (unsigned short*)alloc((size_t)N * 256 * 2);
  unsigned short* aLo = (unsigned short*)alloc((size_t)N * 256 * 2);
  float* eeCsr   = (float*)alloc((size_t)Etot * 4 * 4);
  float* als     = (float*)alloc((size_t)N * 4 * 4);
  float* ald     = (float*)alloc((size_t)N * 4 * 4);
  int*   counts  = (int*)alloc((size_t)N * 4);
  int*   cursor  = (int*)alloc((size_t)N * 4);
  int*   rowStart= (int*)alloc((size_t)(N + 1) * 4);
  int*   csrSrc  = (int*)alloc((size_t)Etot * 4);
  int*   csrDst  = (int*)alloc((size_t)Etot * 4);
  int*   bsums   = (int*)alloc((size_t)((N + 255) / 256) * 4);
  float* sums    = (float*)alloc(256 * 4);
  float* sumsq   = (float*)alloc(256 * 4);
  float* scale1  = (float*)alloc(256 * 4);
  float* shift1  = (float*)alloc(256 * 4);
  float* scale2  = (float*)alloc(256 * 4);
  float* shift2  = (float*)alloc(256 * 4);
  unsigned short* w1h = (unsigned short*)alloc((size_t)128 * 256 * 2);
  unsigned short* w1l = (unsigned short*)alloc((size_t)128 * 256 * 2);
  unsigned short* w2h = (unsigned short*)alloc((size_t)256 * 256 * 2);
  unsigned short* w2l = (unsigned short*)alloc((size_t)256 * 256 * 2);
  unsigned short* w3h = (unsigned short*)alloc((size_t)256 * 64 * 2);
  unsigned short* w3l = (unsigned short*)alloc((size_t)256 * 64 * 2);

  const int nb = (N + 255) / 256;
  const int ebk = (Etot + 255) / 256;
  const int aggBlocks = (N + 3) / 4;

  // ---- weight prep (frag-ordered bf16 hi/lo) ----
  wprep_kernel<<<(128 * 256 + 255) / 256, 256, 0, stream>>>(W1, w1h, w1l, 128, 256);
  wprep_kernel<<<(256 * 256 + 255) / 256, 256, 0, stream>>>(W2, w2h, w2l, 256, 256);
  wprep_kernel<<<(256 * 64 + 255) / 256, 256, 0, stream>>>(W3, w3h, w3l, 256, 64);

  // ---- CSR build (reused by all 3 layers) ----
  hipMemsetAsync(counts, 0, (size_t)N * 4, stream);
  hipMemsetAsync(cursor, 0, (size_t)N * 4, stream);
  count_kernel<<<ebk, 256, 0, stream>>>(dstIdx, E, Etot, counts);
  block_sum_kernel<<<nb, 256, 0, stream>>>(counts, N, bsums);
  scan_bsums_kernel<<<1, 256, 0, stream>>>(bsums, nb);
  scan_write_kernel<<<nb, 256, 0, stream>>>(counts, N, bsums, rowStart, Etot);
  fill_kernel<<<ebk, 256, 0, stream>>>(srcIdx, dstIdx, E, Etot, rowStart, cursor, csrSrc, csrDst);

  dim3 g12((N + 127) / 128, 2);   // layers 1,2: BM=128, BN=128, N=256
  dim3 g3((N + 255) / 256, 1);    // layer 3: BM=256, BN=64

  // ---- GAT layer 1: x[N,128] -> act[N,256] (bias cancels in BN) ----
  split_kernel<<<2048, 256, 0, stream>>>(x, aHi, aLo, (size_t)N * 128 / 4);  // aHi/aLo as [N][128]
  gemm_mfma<2, 2><<<g12, 256, 0, stream>>>(aHi, aLo, w1h, w1l, h16, N, 256, 128);
  al_kernel<4><<<N, 256, 0, stream>>>(h16, a1s, a1d, als, ald, N);
  edge_kernel<4><<<(Etot * 4 + 255) / 256, 256, 0, stream>>>(csrSrc, csrDst, Etot, als, ald, eeCsr);
  aggregate_kernel<256><<<aggBlocks, 256, 0, stream>>>(h16, eeCsr, csrSrc, rowStart, act, N, nullptr, 0);
  // BN1 stats -> scale1/shift1
  hipMemsetAsync(sums, 0, 256 * 4, stream);
  hipMemsetAsync(sumsq, 0, 256 * 4, stream);
  bn_stats_kernel<<<512, 256, 0, stream>>>(act, N, sums, sumsq);
  bn_final_kernel<<<1, 256, 0, stream>>>(sums, sumsq, g1, be1, N, scale1, shift1);

  // ---- GAT layer 2: elu(bn(act)) @ W2 -> h16 ----
  bnsplit_kernel<<<2048, 256, 0, stream>>>(act, scale1, shift1, aHi, aLo, (size_t)N * 256 / 4);
  gemm_mfma<2, 2><<<g12, 256, 0, stream>>>(aHi, aLo, w2h, w2l, h16, N, 256, 256);
  al_kernel<4><<<N, 256, 0, stream>>>(h16, a2s, a2d, als, ald, N);
  edge_kernel<4><<<(Etot * 4 + 255) / 256, 256, 0, stream>>>(csrSrc, csrDst, Etot, als, ald, eeCsr);
  aggregate_kernel<256><<<aggBlocks, 256, 0, stream>>>(h16, eeCsr, csrSrc, rowStart, act, N, nullptr, 0);
  // BN2 stats -> scale2/shift2
  hipMemsetAsync(sums, 0, 256 * 4, stream);
  hipMemsetAsync(sumsq, 0, 256 * 4, stream);
  bn_stats_kernel<<<512, 256, 0, stream>>>(act, N, sums, sumsq);
  bn_final_kernel<<<1, 256, 0, stream>>>(sums, sumsq, g2, be2, N, scale2, shift2);

  // ---- GAT layer 3 (1 head, C=64): elu(bn(act)) @ W3 -> h16[N,64]; agg +b3, ELU ----
  bnsplit_kernel<<<2048, 256, 0, stream>>>(act, scale2, shift2, aHi, aLo, (size_t)N * 256 / 4);
  gemm_mfma<4, 1><<<g3, 256, 0, stream>>>(aHi, aLo, w3h, w3l, h16, N, 64, 256);
  al_kernel<1><<<N, 64, 0, stream>>>(h16, a3s, a3d, als, ald, N);
  edge_kernel<1><<<(Etot + 255) / 256, 256, 0, stream>>>(csrSrc, csrDst, Etot, als, ald, eeCsr);
  aggregate_kernel<64><<<aggBlocks, 256, 0, stream>>>(h16, eeCsr, csrSrc, rowStart, act, N, b3, 1);

  // ---- MLP head ----
  mlp_kernel<<<1024, 256, 0, stream>>>(act, fw1, fb1, fw2, fb2, out, N);
}

// Round 7
// 442.234 us; speedup vs baseline: 2.6956x; 1.0981x over previous
//
#include <hip/hip_runtime.h>
#include <math.h>
#include <stdint.h>

typedef __attribute__((ext_vector_type(8))) short short8v;
typedef __attribute__((ext_vector_type(4))) float float4v;

// ---------------- utility ----------------
__device__ __forceinline__ float warp_sum64(float v) {
#pragma unroll
  for (int off = 32; off; off >>= 1) v += __shfl_xor(v, off);
  return v;
}

__device__ __forceinline__ float bf2f(unsigned short u) {
  return __uint_as_float((unsigned int)u << 16);
}
__device__ __forceinline__ unsigned short f2bf(float f) {   // RNE
  unsigned int u = __float_as_uint(f);
  unsigned int r = (u + 0x7FFFu + ((u >> 16) & 1u)) >> 16;
  return (unsigned short)r;
}

// ---------------- weight prep: fp32 W[K][Nw] -> hi/lo bf16 in MFMA-frag order ----
__global__ void wprep_kernel(const float* __restrict__ W, unsigned short* __restrict__ Wh,
                             unsigned short* __restrict__ Wl, int K, int Nw)
{
  int t = blockIdx.x * 256 + threadIdx.x;
  if (t >= K * Nw) return;
  int i = t & 7;
  int lane = (t >> 3) & 63;
  int frag = t >> 9;
  int ktiles = K >> 5;
  int n_tile = frag / ktiles, k_tile = frag - n_tile * ktiles;
  int k = k_tile * 32 + ((lane >> 4) << 3) + i;
  int n = (n_tile << 4) + (lane & 15);
  float v = W[(size_t)k * Nw + n];
  unsigned short hi = (unsigned short)(__float_as_uint(v) >> 16);   // trunc
  float rem = v - bf2f(hi);
  Wh[t] = hi;
  Wl[t] = f2bf(rem);
}

// ---------------- A-side split passes (conversion done ONCE, outside GEMM) ----
__global__ __launch_bounds__(256) void split_kernel(const float* __restrict__ in,
    unsigned short* __restrict__ hi, unsigned short* __restrict__ lo, size_t n4)
{
  size_t i0 = (size_t)blockIdx.x * 256 + threadIdx.x;
  size_t stride = (size_t)gridDim.x * 256;
  for (size_t idx = i0; idx < n4; idx += stride) {
    float4 v = ((const float4*)in)[idx];
    float vv[4] = {v.x, v.y, v.z, v.w};
    ushort4 h, l;
    unsigned short* hp = &h.x; unsigned short* lp = &l.x;
#pragma unroll
    for (int j = 0; j < 4; ++j) {
      unsigned short hh = (unsigned short)(__float_as_uint(vv[j]) >> 16);
      hp[j] = hh;
      lp[j] = f2bf(vv[j] - bf2f(hh));
    }
    ((ushort4*)hi)[idx] = h;
    ((ushort4*)lo)[idx] = l;
  }
}

// BN(scale,shift) + ELU + split: act [N][256] fp32 -> hi/lo bf16
__global__ __launch_bounds__(256) void bnsplit_kernel(const float* __restrict__ act,
    const float* __restrict__ scale, const float* __restrict__ shift,
    unsigned short* __restrict__ hi, unsigned short* __restrict__ lo, size_t n4)
{
  size_t i0 = (size_t)blockIdx.x * 256 + threadIdx.x;
  size_t stride = (size_t)gridDim.x * 256;
  for (size_t idx = i0; idx < n4; idx += stride) {
    float4 v = ((const float4*)act)[idx];
    int f = (int)((idx * 4) & 255);
    float4 sc = *(const float4*)(scale + f);
    float4 sh = *(const float4*)(shift + f);
    float vv[4];
    vv[0] = fmaf(v.x, sc.x, sh.x);
    vv[1] = fmaf(v.y, sc.y, sh.y);
    vv[2] = fmaf(v.z, sc.z, sh.z);
    vv[3] = fmaf(v.w, sc.w, sh.w);
    ushort4 h, l;
    unsigned short* hp = &h.x; unsigned short* lp = &l.x;
#pragma unroll
    for (int j = 0; j < 4; ++j) {
      float t = vv[j];
      t = t > 0.f ? t : expm1f(t);                 // ELU
      unsigned short hh = (unsigned short)(__float_as_uint(t) >> 16);
      hp[j] = hh;
      lp[j] = f2bf(t - bf2f(hh));
    }
    ((ushort4*)hi)[idx] = h;
    ((ushort4*)lo)[idx] = l;
  }
}

// ---------------- MFMA GEMM: C[M,Nw](bf16) = (Ah+Al)[M,K] @ (Bh+Bl) ----------------
template<int WM, int WN>
__global__ __launch_bounds__(256) void gemm_mfma(
    const unsigned short* __restrict__ Ah, const unsigned short* __restrict__ Al,
    const unsigned short* __restrict__ Bh, const unsigned short* __restrict__ Bl,
    unsigned short* __restrict__ C, int M, int Nw, int K)
{
  constexpr int BM = WM * 64, BN = WN * 64;
  const int wid = threadIdx.x >> 6, lane = threadIdx.x & 63;
  const int wm = wid / WN, wn = wid % WN;
  const int m0 = blockIdx.x * BM + wm * 64;
  const int n0 = blockIdx.y * BN + wn * 64;
  const int ar = lane & 15;
  const int kb = (lane >> 4) << 3;
  const int ktiles = K >> 5;
  const int ntile0 = n0 >> 4;

  float4v acc[4][4];
#pragma unroll
  for (int mi = 0; mi < 4; ++mi)
#pragma unroll
    for (int ni = 0; ni < 4; ++ni)
      acc[mi][ni] = (float4v){0.f, 0.f, 0.f, 0.f};

  for (int kt = 0; kt < ktiles; ++kt) {
    const int kk = kt * 32 + kb;
    short8v bh[4], bl[4];
#pragma unroll
    for (int ni = 0; ni < 4; ++ni) {
      size_t off = (((size_t)(ntile0 + ni) * ktiles + kt) * 64 + lane) * 8;
      bh[ni] = *(const short8v*)(Bh + off);
      bl[ni] = *(const short8v*)(Bl + off);
    }
    short8v ah[4], al_[4];
#pragma unroll
    for (int mi = 0; mi < 4; ++mi) {
      int row = m0 + mi * 16 + ar;
      if (row < M) {
        size_t off = (size_t)row * K + kk;
        ah[mi] = *(const short8v*)(Ah + off);
        al_[mi] = *(const short8v*)(Al + off);
      } else {
        ah[mi] = (short8v){0, 0, 0, 0, 0, 0, 0, 0};
        al_[mi] = (short8v){0, 0, 0, 0, 0, 0, 0, 0};
      }
    }
#pragma unroll
    for (int mi = 0; mi < 4; ++mi)
#pragma unroll
      for (int ni = 0; ni < 4; ++ni) {
        acc[mi][ni] = __builtin_amdgcn_mfma_f32_16x16x32_bf16(ah[mi], bh[ni], acc[mi][ni], 0, 0, 0);
        acc[mi][ni] = __builtin_amdgcn_mfma_f32_16x16x32_bf16(ah[mi], bl[ni], acc[mi][ni], 0, 0, 0);
        acc[mi][ni] = __builtin_amdgcn_mfma_f32_16x16x32_bf16(al_[mi], bh[ni], acc[mi][ni], 0, 0, 0);
      }
  }
  const int cc = lane & 15;
#pragma unroll
  for (int mi = 0; mi < 4; ++mi) {
    int rowb = m0 + mi * 16 + ((lane >> 4) << 2);
#pragma unroll
    for (int r = 0; r < 4; ++r) {
      int row = rowb + r;
      if (row < M) {
#pragma unroll
        for (int ni = 0; ni < 4; ++ni)
          C[(size_t)row * Nw + n0 + ni * 16 + cc] = f2bf(acc[mi][ni][r]);
      }
    }
  }
}

// ---------------- attention logits from bf16 h ----------------
template<int H>
__global__ void al_kernel(const unsigned short* __restrict__ h, const float* __restrict__ a_s,
                          const float* __restrict__ a_d, float* __restrict__ al_s,
                          float* __restrict__ al_d, int N)
{
  int n = blockIdx.x;
  int tid = threadIdx.x;
  int hh = tid >> 6, lane = tid & 63;
  float hv = bf2f(h[(size_t)n * (H * 64) + tid]);
  float ps = hv * a_s[tid];
  float pd = hv * a_d[tid];
  ps = warp_sum64(ps);
  pd = warp_sum64(pd);
  if (lane == 0) { al_s[n * H + hh] = ps; al_d[n * H + hh] = pd; }
}

// ---------------- per-position exp(leaky_relu), CSR order, no atomics ----------------
template<int H>
__global__ void edge_kernel(const int* __restrict__ csrSrc, const int* __restrict__ csrDst,
                            int Etot, const float* __restrict__ al_s,
                            const float* __restrict__ al_d, float* __restrict__ eeCsr)
{
  int t = blockIdx.x * 256 + threadIdx.x;
  if (t >= Etot * H) return;
  int pos = t / H, hh = t - pos * H;
  int s = csrSrc[pos], d = csrDst[pos];
  float x = al_s[s * H + hh] + al_d[d * H + hh];
  x = x > 0.f ? x : 0.2f * x;           // leaky_relu(0.2)
  eeCsr[t] = expf(x);                    // softmax shift-invariant: skip segment max
}

// ---------------- CSR build ----------------
__global__ void count_kernel(const int* __restrict__ dst, int E, int Etot, int* __restrict__ counts)
{
  int e = blockIdx.x * 256 + threadIdx.x;
  if (e >= Etot) return;
  int d = (e < E) ? dst[e] : (e - E);
  atomicAdd(&counts[d], 1);
}

__global__ void block_sum_kernel(const int* __restrict__ counts, int N, int* __restrict__ bsums)
{
  __shared__ int sd[256];
  int i = blockIdx.x * 256 + threadIdx.x;
  sd[threadIdx.x] = (i < N) ? counts[i] : 0;
  __syncthreads();
  for (int off = 128; off; off >>= 1) {
    if (threadIdx.x < off) sd[threadIdx.x] += sd[threadIdx.x + off];
    __syncthreads();
  }
  if (threadIdx.x == 0) bsums[blockIdx.x] = sd[0];
}

// one-block parallel exclusive scan over bsums (nb <= 256)
__global__ void scan_bsums_kernel(int* bsums, int nb)
{
  __shared__ int sd[256];
  int t = threadIdx.x;
  int v = (t < nb) ? bsums[t] : 0;
  sd[t] = v;
  __syncthreads();
  for (int off = 1; off < 256; off <<= 1) {
    int x = (t >= off) ? sd[t - off] : 0;
    __syncthreads();
    sd[t] += x;
    __syncthreads();
  }
  if (t < nb) bsums[t] = sd[t] - v;  // exclusive
}

__global__ void scan_write_kernel(const int* __restrict__ counts, int N,
                                  const int* __restrict__ bsums, int* __restrict__ rowStart, int Etot)
{
  __shared__ int sd[256];
  int i = blockIdx.x * 256 + threadIdx.x;
  int v = (i < N) ? counts[i] : 0;
  sd[threadIdx.x] = v;
  __syncthreads();
  for (int off = 1; off < 256; off <<= 1) {
    int x = (threadIdx.x >= off) ? sd[threadIdx.x - off] : 0;
    __syncthreads();
    sd[threadIdx.x] += x;
    __syncthreads();
  }
  if (i < N) rowStart[i] = bsums[blockIdx.x] + sd[threadIdx.x] - v;  // exclusive
  if (i == N - 1) rowStart[N] = Etot;
}

__global__ void fill_kernel(const int* __restrict__ src, const int* __restrict__ dst,
                            int E, int Etot, const int* __restrict__ rowStart,
                            int* __restrict__ cursor, int* __restrict__ csrSrc,
                            int* __restrict__ csrDst)
{
  int e = blockIdx.x * 256 + threadIdx.x;
  if (e >= Etot) return;
  int s, d;
  if (e < E) { s = src[e]; d = dst[e]; } else { s = d = e - E; }
  int pos = rowStart[d] + atomicAdd(&cursor[d], 1);
  csrSrc[pos] = s;
  csrDst[pos] = d;
}

// ---------------- aggregation: wave per node, bf16 gather, inline denom, 4x ILP ----
template<int HC_>
__global__ __launch_bounds__(256) void aggregate_kernel(
    const unsigned short* __restrict__ h16, const float* __restrict__ eeCsr,
    const int* __restrict__ csrSrc, const int* __restrict__ rowStart,
    float* __restrict__ outp, int N, const float* __restrict__ bias, int doElu)
{
  constexpr int H_ = HC_ / 64;       // heads (4 or 1)
  constexpr int FPL = HC_ / 64;      // features per lane (4 or 1)
  int wid = (int)(blockIdx.x * (blockDim.x >> 6) + (threadIdx.x >> 6));
  if (wid >= N) return;
  const int lane = threadIdx.x & 63;
  const int head = (H_ == 4) ? (lane >> 4) : 0;
  const int start = rowStart[wid], end = rowStart[wid + 1];

  float acc[FPL] = {};
  float wsum = 0.f;

  for (int base = start; base < end; base += 64) {
    int cnt = end - base; if (cnt > 64) cnt = 64;
    int s_l = (lane < cnt) ? csrSrc[base + lane] : 0;
    int i = 0;
    for (; i + 4 <= cnt; i += 4) {
      int s0 = __shfl(s_l, i);
      int s1 = __shfl(s_l, i + 1);
      int s2 = __shfl(s_l, i + 2);
      int s3 = __shfl(s_l, i + 3);
      float w0 = eeCsr[(size_t)(base + i) * H_ + head];
      float w1 = eeCsr[(size_t)(base + i + 1) * H_ + head];
      float w2 = eeCsr[(size_t)(base + i + 2) * H_ + head];
      float w3 = eeCsr[(size_t)(base + i + 3) * H_ + head];
      if (FPL == 4) {
        ushort4 r0 = ((const ushort4*)(h16 + (size_t)s0 * HC_))[lane];
        ushort4 r1 = ((const ushort4*)(h16 + (size_t)s1 * HC_))[lane];
        ushort4 r2 = ((const ushort4*)(h16 + (size_t)s2 * HC_))[lane];
        ushort4 r3 = ((const ushort4*)(h16 + (size_t)s3 * HC_))[lane];
        wsum += (w0 + w1) + (w2 + w3);
        acc[0] = fmaf(w0, bf2f(r0.x), acc[0]);
        acc[1] = fmaf(w0, bf2f(r0.y), acc[1]);
        acc[2] = fmaf(w0, bf2f(r0.z), acc[2]);
        acc[3] = fmaf(w0, bf2f(r0.w), acc[3]);
        acc[0] = fmaf(w1, bf2f(r1.x), acc[0]);
        acc[1] = fmaf(w1, bf2f(r1.y), acc[1]);
        acc[2] = fmaf(w1, bf2f(r1.z), acc[2]);
        acc[3] = fmaf(w1, bf2f(r1.w), acc[3]);
        acc[0] = fmaf(w2, bf2f(r2.x), acc[0]);
        acc[1] = fmaf(w2, bf2f(r2.y), acc[1]);
        acc[2] = fmaf(w2, bf2f(r2.z), acc[2]);
        acc[3] = fmaf(w2, bf2f(r2.w), acc[3]);
        acc[0] = fmaf(w3, bf2f(r3.x), acc[0]);
        acc[1] = fmaf(w3, bf2f(r3.y), acc[1]);
        acc[2] = fmaf(w3, bf2f(r3.z), acc[2]);
        acc[3] = fmaf(w3, bf2f(r3.w), acc[3]);
      } else {
        unsigned short r0 = h16[(size_t)s0 * HC_ + lane];
        unsigned short r1 = h16[(size_t)s1 * HC_ + lane];
        unsigned short r2 = h16[(size_t)s2 * HC_ + lane];
        unsigned short r3 = h16[(size_t)s3 * HC_ + lane];
        wsum += (w0 + w1) + (w2 + w3);
        acc[0] = fmaf(w0, bf2f(r0), acc[0]);
        acc[0] = fmaf(w1, bf2f(r1), acc[0]);
        acc[0] = fmaf(w2, bf2f(r2), acc[0]);
        acc[0] = fmaf(w3, bf2f(r3), acc[0]);
      }
    }
    for (; i < cnt; ++i) {
      int s0 = __shfl(s_l, i);
      float w0 = eeCsr[(size_t)(base + i) * H_ + head];
      wsum += w0;
      if (FPL == 4) {
        ushort4 r0 = ((const ushort4*)(h16 + (size_t)s0 * HC_))[lane];
        acc[0] = fmaf(w0, bf2f(r0.x), acc[0]);
        acc[1] = fmaf(w0, bf2f(r0.y), acc[1]);
        acc[2] = fmaf(w0, bf2f(r0.z), acc[2]);
        acc[3] = fmaf(w0, bf2f(r0.w), acc[3]);
      } else {
        unsigned short r0 = h16[(size_t)s0 * HC_ + lane];
        acc[0] = fmaf(w0, bf2f(r0), acc[0]);
      }
    }
  }

  float inv = 1.0f / wsum;
  if (FPL == 4) {
    float4 o;
    o.x = acc[0] * inv; o.y = acc[1] * inv; o.z = acc[2] * inv; o.w = acc[3] * inv;
    if (bias) {
      const float4 b = ((const float4*)bias)[lane];
      o.x += b.x; o.y += b.y; o.z += b.z; o.w += b.w;
    }
    if (doElu) {
      o.x = o.x > 0.f ? o.x : expm1f(o.x);
      o.y = o.y > 0.f ? o.y : expm1f(o.y);
      o.z = o.z > 0.f ? o.z : expm1f(o.z);
      o.w = o.w > 0.f ? o.w : expm1f(o.w);
    }
    ((float4*)(outp + (size_t)wid * HC_))[lane] = o;
  } else {
    float o = acc[0] * inv;
    if (bias) o += bias[lane];
    if (doElu) o = o > 0.f ? o : expm1f(o);
    outp[(size_t)wid * HC_ + lane] = o;
  }
}

// ---------------- batch norm stats: wave-per-row-group, float4, LDS reduce ----------------
__global__ __launch_bounds__(256) void bn_stats_kernel(const float* __restrict__ x, int N,
                                float* __restrict__ sums, float* __restrict__ sumsq)
{
  const int wid = threadIdx.x >> 6, lane = threadIdx.x & 63;
  const int gw = blockIdx.x * 4 + wid;         // global wave id
  const int tw = gridDim.x * 4;                // total waves
  float4 s = make_float4(0.f, 0.f, 0.f, 0.f);
  float4 q = make_float4(0.f, 0.f, 0.f, 0.f);
#pragma unroll 4
  for (int r = gw; r < N; r += tw) {
    float4 v = ((const float4*)(x + (size_t)r * 256))[lane];
    s.x += v.x; s.y += v.y; s.z += v.z; s.w += v.w;
    q.x = fmaf(v.x, v.x, q.x); q.y = fmaf(v.y, v.y, q.y);
    q.z = fmaf(v.z, v.z, q.z); q.w = fmaf(v.w, v.w, q.w);
  }
  __shared__ float ls[4][512];
  *(float4*)&ls[wid][lane * 4] = s;
  *(float4*)&ls[wid][256 + lane * 4] = q;
  __syncthreads();
  const int t = threadIdx.x;
  float a = ls[0][t] + ls[1][t] + ls[2][t] + ls[3][t];
  float b = ls[0][t + 256] + ls[1][t + 256] + ls[2][t + 256] + ls[3][t + 256];
  atomicAdd(&sums[t], a);
  atomicAdd(&sumsq[t], b);
}

__global__ void bn_final_kernel(const float* __restrict__ sums, const float* __restrict__ sumsq,
                                const float* __restrict__ g, const float* __restrict__ be,
                                int N, float* __restrict__ scale, float* __restrict__ shift)
{
  int f = threadIdx.x;
  float mu = sums[f] / N;
  float var = sumsq[f] / N - mu * mu;
  float rs = rsqrtf(var + 1e-5f);
  float sc = g[f] * rs;
  scale[f] = sc;
  shift[f] = be[f] - mu * sc;
}

// ---------------- MLP head: thread-per-node, LDS weight broadcast, no cross-lane ops ----
__global__ __launch_bounds__(256) void mlp_kernel(const float* __restrict__ h,
                           const float* __restrict__ fw1,
                           const float* __restrict__ fb1, const float* __restrict__ fw2,
                           const float* __restrict__ fb2, float* __restrict__ out, int N)
{
  __shared__ float w1s[64][32];   // fw1 [k][j]
  __shared__ float w2s[32][2];
  __shared__ float b1s[32];
  const int t = threadIdx.x;
  for (int i = t; i < 64 * 32; i += 256) w1s[i >> 5][i & 31] = fw1[i];
  if (t < 64) w2s[t >> 1][t & 1] = fw2[t];
  if (t < 32) b1s[t] = fb1[t];
  __syncthreads();

  int n = blockIdx.x * 256 + t;   // one node per thread
  if (n >= N) return;

  // load h row into registers (16x float4)
  float hv[64];
#pragma unroll
  for (int k4 = 0; k4 < 16; ++k4) {
    float4 v = *(const float4*)(h + (size_t)n * 64 + k4 * 4);
    hv[k4 * 4 + 0] = v.x; hv[k4 * 4 + 1] = v.y;
    hv[k4 * 4 + 2] = v.z; hv[k4 * 4 + 3] = v.w;
  }
  // hidden layer: 32 independent accumulators, LDS reads are uniform broadcasts
  float hid[32];
#pragma unroll
  for (int j = 0; j < 32; ++j) hid[j] = b1s[j];
#pragma unroll
  for (int k = 0; k < 64; ++k) {
    float hk = hv[k];
#pragma unroll
    for (int jb = 0; jb < 8; ++jb) {
      float4 wv = *(const float4*)&w1s[k][jb * 4];
      hid[jb * 4 + 0] = fmaf(hk, wv.x, hid[jb * 4 + 0]);
      hid[jb * 4 + 1] = fmaf(hk, wv.y, hid[jb * 4 + 1]);
      hid[jb * 4 + 2] = fmaf(hk, wv.z, hid[jb * 4 + 2]);
      hid[jb * 4 + 3] = fmaf(hk, wv.w, hid[jb * 4 + 3]);
    }
  }
  // output layer
  float p0 = fb2[0], p1 = fb2[1];
#pragma unroll
  for (int j = 0; j < 32; ++j) {
    float r = fmaxf(hid[j], 0.f);
    p0 = fmaf(r, w2s[j][0], p0);
    p1 = fmaf(r, w2s[j][1], p1);
  }
  *(float2*)(out + (size_t)n * 2) = make_float2(p0, p1);
}

// ---------------- host ----------------
extern "C" void kernel_launch(void* const* d_in, const int* in_sizes, int n_in,
                              void* d_out, int out_size, void* d_ws, size_t ws_size,
                              hipStream_t stream)
{
  const float* x   = (const float*)d_in[0];
  const int*   ei  = (const int*)d_in[1];
  const float* W1  = (const float*)d_in[2];
  const float* a1s = (const float*)d_in[3];
  const float* a1d = (const float*)d_in[4];
  const float* W2  = (const float*)d_in[6];
  const float* a2s = (const float*)d_in[7];
  const float* a2d = (const float*)d_in[8];
  const float* W3  = (const float*)d_in[10];
  const float* a3s = (const float*)d_in[11];
  const float* a3d = (const float*)d_in[12];
  const float* b3  = (const float*)d_in[13];
  const float* g1  = (const float*)d_in[14];
  const float* be1 = (const float*)d_in[15];
  const float* g2  = (const float*)d_in[16];
  const float* be2 = (const float*)d_in[17];
  const float* fw1 = (const float*)d_in[18];
  const float* fb1 = (const float*)d_in[19];
  const float* fw2 = (const float*)d_in[20];
  const float* fb2 = (const float*)d_in[21];
  float* out = (float*)d_out;

  const int F = 128;
  const int N = in_sizes[0] / F;
  const int E = in_sizes[1] / 2;
  const int Etot = E + N;
  const int* srcIdx = ei;
  const int* dstIdx = ei + E;

  // workspace layout (256B aligned slices)
  char* w = (char*)d_ws;
  auto alloc = [&](size_t bytes) -> void* {
    void* p = (void*)w;
    w += (bytes + 255) & ~(size_t)255;
    return p;
  };
  unsigned short* h16 = (unsigned short*)alloc((size_t)N * 256 * 2);
  float* act     = (float*)alloc((size_t)N * 256 * 4);
  unsigned short* aHi = (unsigned short*)alloc((size_t)N * 256 * 2);
  unsigned short* aLo = (unsigned short*)alloc((size_t)N * 256 * 2);
  float* eeCsr   = (float*)alloc((size_t)Etot * 4 * 4);
  float* als     = (float*)alloc((size_t)N * 4 * 4);
  float* ald     = (float*)alloc((size_t)N * 4 * 4);
  int*   counts  = (int*)alloc((size_t)N * 4);
  int*   cursor  = (int*)alloc((size_t)N * 4);
  int*   rowStart= (int*)alloc((size_t)(N + 1) * 4);
  int*   csrSrc  = (int*)alloc((size_t)Etot * 4);
  int*   csrDst  = (int*)alloc((size_t)Etot * 4);
  int*   bsums   = (int*)alloc((size_t)((N + 255) / 256) * 4);
  float* sums    = (float*)alloc(256 * 4);
  float* sumsq   = (float*)alloc(256 * 4);
  float* scale1  = (float*)alloc(256 * 4);
  float* shift1  = (float*)alloc(256 * 4);
  float* scale2  = (float*)alloc(256 * 4);
  float* shift2  = (float*)alloc(256 * 4);
  unsigned short* w1h = (unsigned short*)alloc((size_t)128 * 256 * 2);
  unsigned short* w1l = (unsigned short*)alloc((size_t)128 * 256 * 2);
  unsigned short* w2h = (unsigned short*)alloc((size_t)256 * 256 * 2);
  unsigned short* w2l = (unsigned short*)alloc((size_t)256 * 256 * 2);
  unsigned short* w3h = (unsigned short*)alloc((size_t)256 * 64 * 2);
  unsigned short* w3l = (unsigned short*)alloc((size_t)256 * 64 * 2);

  const int nb = (N + 255) / 256;
  const int ebk = (Etot + 255) / 256;
  const int aggBlocks = (N + 3) / 4;

  // ---- weight prep (frag-ordered bf16 hi/lo) ----
  wprep_kernel<<<(128 * 256 + 255) / 256, 256, 0, stream>>>(W1, w1h, w1l, 128, 256);
  wprep_kernel<<<(256 * 256 + 255) / 256, 256, 0, stream>>>(W2, w2h, w2l, 256, 256);
  wprep_kernel<<<(256 * 64 + 255) / 256, 256, 0, stream>>>(W3, w3h, w3l, 256, 64);

  // ---- CSR build (reused by all 3 layers) ----
  hipMemsetAsync(counts, 0, (size_t)N * 4, stream);
  hipMemsetAsync(cursor, 0, (size_t)N * 4, stream);
  count_kernel<<<ebk, 256, 0, stream>>>(dstIdx, E, Etot, counts);
  block_sum_kernel<<<nb, 256, 0, stream>>>(counts, N, bsums);
  scan_bsums_kernel<<<1, 256, 0, stream>>>(bsums, nb);
  scan_write_kernel<<<nb, 256, 0, stream>>>(counts, N, bsums, rowStart, Etot);
  fill_kernel<<<ebk, 256, 0, stream>>>(srcIdx, dstIdx, E, Etot, rowStart, cursor, csrSrc, csrDst);

  dim3 g12((N + 127) / 128, 2);   // layers 1,2: BM=128, BN=128, N=256
  dim3 g3((N + 255) / 256, 1);    // layer 3: BM=256, BN=64

  // ---- GAT layer 1: x[N,128] -> act[N,256] (bias cancels in BN) ----
  split_kernel<<<2048, 256, 0, stream>>>(x, aHi, aLo, (size_t)N * 128 / 4);  // aHi/aLo as [N][128]
  gemm_mfma<2, 2><<<g12, 256, 0, stream>>>(aHi, aLo, w1h, w1l, h16, N, 256, 128);
  al_kernel<4><<<N, 256, 0, stream>>>(h16, a1s, a1d, als, ald, N);
  edge_kernel<4><<<(Etot * 4 + 255) / 256, 256, 0, stream>>>(csrSrc, csrDst, Etot, als, ald, eeCsr);
  aggregate_kernel<256><<<aggBlocks, 256, 0, stream>>>(h16, eeCsr, csrSrc, rowStart, act, N, nullptr, 0);
  // BN1 stats -> scale1/shift1
  hipMemsetAsync(sums, 0, 256 * 4, stream);
  hipMemsetAsync(sumsq, 0, 256 * 4, stream);
  bn_stats_kernel<<<512, 256, 0, stream>>>(act, N, sums, sumsq);
  bn_final_kernel<<<1, 256, 0, stream>>>(sums, sumsq, g1, be1, N, scale1, shift1);

  // ---- GAT layer 2: elu(bn(act)) @ W2 -> h16 ----
  bnsplit_kernel<<<2048, 256, 0, stream>>>(act, scale1, shift1, aHi, aLo, (size_t)N * 256 / 4);
  gemm_mfma<2, 2><<<g12, 256, 0, stream>>>(aHi, aLo, w2h, w2l, h16, N, 256, 256);
  al_kernel<4><<<N, 256, 0, stream>>>(h16, a2s, a2d, als, ald, N);
  edge_kernel<4><<<(Etot * 4 + 255) / 256, 256, 0, stream>>>(csrSrc, csrDst, Etot, als, ald, eeCsr);
  aggregate_kernel<256><<<aggBlocks, 256, 0, stream>>>(h16, eeCsr, csrSrc, rowStart, act, N, nullptr, 0);
  // BN2 stats -> scale2/shift2
  hipMemsetAsync(sums, 0, 256 * 4, stream);
  hipMemsetAsync(sumsq, 0, 256 * 4, stream);
  bn_stats_kernel<<<512, 256, 0, stream>>>(act, N, sums, sumsq);
  bn_final_kernel<<<1, 256, 0, stream>>>(sums, sumsq, g2, be2, N, scale2, shift2);

  // ---- GAT layer 3 (1 head, C=64): elu(bn(act)) @ W3 -> h16[N,64]; agg +b3, ELU ----
  bnsplit_kernel<<<2048, 256, 0, stream>>>(act, scale2, shift2, aHi, aLo, (size_t)N * 256 / 4);
  gemm_mfma<4, 1><<<g3, 256, 0, stream>>>(aHi, aLo, w3h, w3l, h16, N, 64, 256);
  al_kernel<1><<<N, 64, 0, stream>>>(h16, a3s, a3d, als, ald, N);
  edge_kernel<1><<<(Etot + 255) / 256, 256, 0, stream>>>(csrSrc, csrDst, Etot, als, ald, eeCsr);
  aggregate_kernel<64><<<aggBlocks, 256, 0, stream>>>(h16, eeCsr, csrSrc, rowStart, act, N, b3, 1);

  // ---- MLP head ----
  mlp_kernel<<<(N + 255) / 256, 256, 0, stream>>>(act, fw1, fb1, fw2, fb2, out, N);
}